// Round 9
// baseline (286.064 us; speedup 1.0000x reference)
//
#include <hip/hip_runtime.h>
#include <stdint.h>
#include <math.h>

// Problem constants (B=8192 rows, D=512 features)
#define Bn 8192
#define Dn 512
#define EPSN 1e-12f
#define EPSP 1e-6f
#define MARG 0.3f

// R9: GEMM in MX-fp8 (e4m3, unit scales) via mfma_scale_f32_32x32x64_f8f6f4.
// KT halves 16->8 at identical LDS byte-geometry (BK=64 fp8 = 64 B rows =
// R5's BK=32 bf16), same swizzle (0 conflicts, R5/R8-verified), same 64 AGPR
// acc + ~64 VGPR -> 4 blocks/CU. Rows pre-scaled by 16 (all e4m3-normal);
// scores divided by 256 in epilogue. pos/neg distances stay exact fp32.
#define BM 128
#define BN 128
#define BKB 64          // k-bytes (=elements) per tile
#define KT (Dn / BKB)   // 8 k-iterations
#define NCT (Bn / BN)   // 64 column tiles
#define FSCALE 16.0f
#define ISCALE2 (1.0f / 256.0f)

typedef int   int4v  __attribute__((ext_vector_type(4)));
typedef int   int8v  __attribute__((ext_vector_type(8)));   // 32 B fp8 frag
typedef float f32x16 __attribute__((ext_vector_type(16)));

__device__ __forceinline__ uint16_t f2bf(float f) {
    union { float f; uint32_t u; } c; c.f = f;
    uint32_t r = (c.u + 0x7fffu + ((c.u >> 16) & 1u)) >> 16;
    return (uint16_t)r;
}

// float -> fp8 e4m3fn, RNE, handles subnormals; |x| < 448 assumed (ours <= 16)
__device__ __forceinline__ uint8_t f2fp8(float x) {
    union { float f; uint32_t u; } c; c.f = x;
    const uint32_t s = (c.u >> 24) & 0x80;
    const int32_t e = (int32_t)((c.u >> 23) & 0xFF) - 127;
    const uint32_t m = c.u & 0x7FFFFF;
    if (e >= -6) {                       // normal range of e4m3
        const uint32_t lsb = (m >> 20) & 1;
        const uint32_t r = m + 0x7FFFF + lsb;
        uint32_t m3 = r >> 20;           // 0..8
        int E = e;
        if (m3 >= 8) { m3 = 0; E += 1; }
        return (uint8_t)(s | ((uint32_t)(E + 7) << 3) | m3);
    }
    if (e < -12) return (uint8_t)s;      // underflow to 0
    // subnormal: quantum 2^-9
    const uint32_t mant = m | 0x800000;  // 1.m in 24 bits
    const int rb = 21 + (-6 - e);        // 22..27
    uint32_t res = (rb < 24) ? (mant >> rb) : 0u;
    const uint32_t rem = mant & ((1u << rb) - 1u);
    const uint32_t half = 1u << (rb - 1);
    if (rem > half || (rem == half && (res & 1))) res++;
    if (res >= 8) return (uint8_t)(s | (1u << 3));  // rounds to min normal
    return (uint8_t)(s | res);
}

// async global->LDS, 16B per lane; LDS dest is wave-uniform base + lane*16
__device__ __forceinline__ void async16(const void* g, void* l) {
    __builtin_amdgcn_global_load_lds(
        (const __attribute__((address_space(1))) void*)g,
        (__attribute__((address_space(3))) void*)l,
        16, 0, 0);
}

// ---------------------------------------------------------------------------
// K1: per-row L2 normalize -> fp8 rows (x16 pre-scale), inverse norms,
// column term c[j] = -sp2[j] + 2*eps*sp[j] (exact fp32). One wave per row.
// ---------------------------------------------------------------------------
__global__ __launch_bounds__(256) void k_normalize(
    const float* __restrict__ x,
    uint8_t* __restrict__ a_f8, uint8_t* __restrict__ p_f8,
    float* __restrict__ rnA, float* __restrict__ rnP,
    float* __restrict__ cterm)
{
    const int wave = threadIdx.x >> 6;
    const int lane = threadIdx.x & 63;
    const int r = blockIdx.x * 4 + wave;   // 0..16383
    const int i = r >> 1;
    const int which = r & 1;               // 0 = a-row, 1 = p-row

    const float* src = x + (size_t)i * (2 * Dn) + (size_t)which * Dn + lane * 8;
    float4 lo = ((const float4*)src)[0];
    float4 hi = ((const float4*)src)[1];
    float v[8] = {lo.x, lo.y, lo.z, lo.w, hi.x, hi.y, hi.z, hi.w};

    float ss = 0.f;
#pragma unroll
    for (int j = 0; j < 8; ++j) ss += v[j] * v[j];
#pragma unroll
    for (int m = 1; m < 64; m <<= 1) ss += __shfl_xor(ss, m);
    const float scale = 1.0f / fmaxf(sqrtf(ss), EPSN);

    float o[8], s1 = 0.f, s2 = 0.f;
#pragma unroll
    for (int j = 0; j < 8; ++j) { o[j] = v[j] * scale; s1 += o[j]; s2 += o[j] * o[j]; }

    uint8_t* bdst = (which ? p_f8 : a_f8) + (size_t)i * Dn + lane * 8;
    uint64_t pk = 0;
#pragma unroll
    for (int j = 0; j < 8; ++j)
        pk |= (uint64_t)f2fp8(o[j] * FSCALE) << (8 * j);
    *(uint64_t*)bdst = pk;

    if (which) {
#pragma unroll
        for (int m = 1; m < 64; m <<= 1) { s1 += __shfl_xor(s1, m); s2 += __shfl_xor(s2, m); }
        if (lane == 0) { cterm[i] = -s2 + 2.0f * EPSP * s1; rnP[i] = scale; }
    } else {
        if (lane == 0) rnA[i] = scale;
    }
}

// ---------------------------------------------------------------------------
// K2: fp8 MFMA GEMM (a_n @ p_n^T, x256 scaled) + fused per-row argmax.
// 128x128 block, 4 waves 2x2, wave tile 64x64 = 2x2 mfma 32x32x64.
// A/B frag layout: m(or n) = lane&31, k = (lane>>5)*32 + j (32 contiguous B).
// C/D 32x32: col = lane&31, row = (reg&3) + 8*(reg>>2) + 4*(lane>>5).
// LDS: rows of 64 B, 4 chunks of 16 B, slot = c ^ ((row>>1)&3) (R5 swizzle).
// ---------------------------------------------------------------------------
__global__ __launch_bounds__(256, 4) void k_gemm_argmax(
    const uint8_t* __restrict__ a_f8, const uint8_t* __restrict__ p_f8,
    const float* __restrict__ cterm,
    float* __restrict__ pval, int* __restrict__ pidx)
{
    __shared__ uint8_t As[2][BM * BKB];   // 2 x 8 KB
    __shared__ uint8_t Bs[2][BN * BKB];   // 2 x 8 KB
    __shared__ float rv[2][BM];
    __shared__ int   ri[2][BM];

    const int t = threadIdx.x;
    const int wave = t >> 6;
    const int lane = t & 63;
    const int rowBase = blockIdx.y * BM;
    const int colBase = blockIdx.x * BN;

    const int n32 = lane & 31;     // row/col within 32-tile
    const int h = lane >> 5;       // k-half (0..1)
    const int waveRow = (wave >> 1) * 64;
    const int waveCol = (wave & 1) * 64;

    // --- staging (identical geometry to R5: 512 16B chunks per tile,
    // chunk c -> row c>>2, slot c&3 holds global chunk (c&3)^((row>>1)&3))
    const int r0 = t >> 2;
    const int g0 = (t & 3) ^ ((r0 >> 1) & 3);
    const int r1 = (256 + t) >> 2;
    const int g1 = ((256 + t) & 3) ^ ((r1 >> 1) & 3);
    const uint8_t* gA0 = a_f8 + (size_t)(rowBase + r0) * Dn + g0 * 16;
    const uint8_t* gA1 = a_f8 + (size_t)(rowBase + r1) * Dn + g1 * 16;
    const uint8_t* gB0 = p_f8 + (size_t)(colBase + r0) * Dn + g0 * 16;
    const uint8_t* gB1 = p_f8 + (size_t)(colBase + r1) * Dn + g1 * 16;
    const int ldsC0 = (wave * 64) * 16;          // bytes; HW adds lane*16
    const int ldsC1 = (256 + wave * 64) * 16;

    // --- fragment LDS read bases. hash = ((row>>1)&3) reduces to (n32>>1)&3.
    const int hh = (n32 >> 1) & 3;
    const int slo = (h * 2) ^ hh;        // chunk for k-bytes [h*32, h*32+16)
    const int shi = slo ^ 1;             // chunk for k-bytes [h*32+16, h*32+32)
    const int aOff = (waveRow + n32) * BKB;
    const int bOff = (waveCol + n32) * BKB;

    f32x16 acc[2][2];
#pragma unroll
    for (int a = 0; a < 2; ++a)
#pragma unroll
        for (int b = 0; b < 2; ++b)
#pragma unroll
            for (int e = 0; e < 16; ++e) acc[a][b][e] = 0.f;

    auto stage = [&](int buf, int ke) {
        async16(gA0 + ke, &As[buf][ldsC0]);
        async16(gA1 + ke, &As[buf][ldsC1]);
        async16(gB0 + ke, &Bs[buf][ldsC0]);
        async16(gB1 + ke, &Bs[buf][ldsC1]);
    };

    stage(0, 0);
#pragma unroll
    for (int kt = 0; kt < KT; ++kt) {
        const int cur = kt & 1;
        __syncthreads();                 // tile kt resident; prior buf reads done
        if (kt + 1 < KT) stage(cur ^ 1, (kt + 1) * BKB);  // drains at NEXT barrier

        int8v af[2], bf[2];
#pragma unroll
        for (int mt = 0; mt < 2; ++mt) {
            const uint8_t* pa = &As[cur][aOff + mt * 32 * BKB];
            int4v lo = *(const int4v*)(pa + slo * 16);
            int4v hi = *(const int4v*)(pa + shi * 16);
#pragma unroll
            for (int e = 0; e < 4; ++e) { af[mt][e] = lo[e]; af[mt][4 + e] = hi[e]; }
        }
#pragma unroll
        for (int nt = 0; nt < 2; ++nt) {
            const uint8_t* pb = &Bs[cur][bOff + nt * 32 * BKB];
            int4v lo = *(const int4v*)(pb + slo * 16);
            int4v hi = *(const int4v*)(pb + shi * 16);
#pragma unroll
            for (int e = 0; e < 4; ++e) { bf[nt][e] = lo[e]; bf[nt][4 + e] = hi[e]; }
        }
#pragma unroll
        for (int mt = 0; mt < 2; ++mt)
#pragma unroll
            for (int nt = 0; nt < 2; ++nt)
                acc[mt][nt] = __builtin_amdgcn_mfma_scale_f32_32x32x64_f8f6f4(
                    af[mt], bf[nt], acc[mt][nt],
                    0, 0,                   // cbsz=fp8(e4m3), blgp=fp8(e4m3)
                    0, 0x7F7F7F7F,          // scale_a opsel, scale_a = 1.0 (E8M0 127)
                    0, 0x7F7F7F7F);         // scale_b
    }

    // epilogue: score = 2*dot/256 + c[j]; mask diagonal; per-row argmax
    float cv[2];
#pragma unroll
    for (int nt = 0; nt < 2; ++nt)
        cv[nt] = cterm[colBase + waveCol + nt * 32 + n32];

#pragma unroll
    for (int mt = 0; mt < 2; ++mt) {
#pragma unroll
        for (int reg = 0; reg < 16; ++reg) {
            const int lr = waveRow + mt * 32 + (reg & 3) + 8 * (reg >> 2) + 4 * h;
            const int gi = rowBase + lr;
            float best = -INFINITY;
            int bidx = 0x7fffffff;
#pragma unroll
            for (int nt = 0; nt < 2; ++nt) {
                const int gj = colBase + waveCol + nt * 32 + n32;  // col = lane&31
                float sc = 2.0f * ISCALE2 * acc[mt][nt][reg] + cv[nt];
                if (gj == gi) sc = -INFINITY;
                if (sc > best || (sc == best && gj < bidx)) { best = sc; bidx = gj; }
            }
#pragma unroll
            for (int msk = 1; msk < 32; msk <<= 1) {   // reduce over 32 cols
                float ob = __shfl_xor(best, msk);
                int oi = __shfl_xor(bidx, msk);
                if (ob > best || (ob == best && oi < bidx)) { best = ob; bidx = oi; }
            }
            if (n32 == 0) { rv[wave & 1][lr] = best; ri[wave & 1][lr] = bidx; }
        }
    }
    __syncthreads();
    if (t < BM) {
        float b0 = rv[0][t]; int i0 = ri[0][t];
        float b1 = rv[1][t]; int i1 = ri[1][t];
        if (b1 > b0 || (b1 == b0 && i1 < i0)) { b0 = b1; i0 = i1; }
        const size_t o = (size_t)(rowBase + t) * NCT + blockIdx.x;
        pval[o] = b0;
        pidx[o] = i0;
    }
}

// ---------------------------------------------------------------------------
// K3: reduce 64 partials -> negidx; recompute normalized rows from x + stored
// inverse norms; pos/neg distances fp32 per reference; relu -> rowloss.
// One wave per row. (Non-atomic: single-address atomicAdd costs ~100us.)
// ---------------------------------------------------------------------------
__global__ __launch_bounds__(256) void k_rowloss(
    const float* __restrict__ x,
    const float* __restrict__ rnA, const float* __restrict__ rnP,
    const float* __restrict__ pval, const int* __restrict__ pidx,
    float* __restrict__ rowloss)
{
    const int wave = threadIdx.x >> 6;
    const int lane = threadIdx.x & 63;
    const int i = blockIdx.x * 4 + wave;

    float best = pval[(size_t)i * NCT + lane];
    int bidx = pidx[(size_t)i * NCT + lane];
#pragma unroll
    for (int msk = 1; msk < 64; msk <<= 1) {
        float ob = __shfl_xor(best, msk);
        int oi = __shfl_xor(bidx, msk);
        if (ob > best || (ob == best && oi < bidx)) { best = ob; bidx = oi; }
    }

    const float ra = rnA[i];
    const float rp = rnP[i];
    const float rn = rnP[bidx];
    const float4* av = (const float4*)(x + (size_t)i * (2 * Dn));
    const float4* pv = (const float4*)(x + (size_t)i * (2 * Dn) + Dn);
    const float4* nv = (const float4*)(x + (size_t)bidx * (2 * Dn) + Dn);
    float pos = 0.f, ng = 0.f;
#pragma unroll
    for (int c = 0; c < 2; ++c) {
        const int idx = lane + c * 64;
        float4 a4 = av[idx], p4 = pv[idx], n4 = nv[idx];
        float u;
        u = a4.x * ra - p4.x * rp + EPSP; pos += u * u;
        u = a4.y * ra - p4.y * rp + EPSP; pos += u * u;
        u = a4.z * ra - p4.z * rp + EPSP; pos += u * u;
        u = a4.w * ra - p4.w * rp + EPSP; pos += u * u;
        u = a4.x * ra - n4.x * rn + EPSP; ng += u * u;
        u = a4.y * ra - n4.y * rn + EPSP; ng += u * u;
        u = a4.z * ra - n4.z * rn + EPSP; ng += u * u;
        u = a4.w * ra - n4.w * rn + EPSP; ng += u * u;
    }
#pragma unroll
    for (int msk = 1; msk < 64; msk <<= 1) {
        pos += __shfl_xor(pos, msk);
        ng += __shfl_xor(ng, msk);
    }
    if (lane == 0) rowloss[i] = fmaxf(pos - ng + MARG, 0.f);
}

// ---------------------------------------------------------------------------
// K4: mean over 8192 row losses -> scalar out (deterministic)
// ---------------------------------------------------------------------------
__global__ __launch_bounds__(1024) void k_final(
    const float* __restrict__ rowloss, float* __restrict__ out)
{
    __shared__ float sm[16];
    float s = 0.f;
    for (int k = threadIdx.x; k < Bn; k += 1024) s += rowloss[k];
#pragma unroll
    for (int msk = 1; msk < 64; msk <<= 1) s += __shfl_xor(s, msk);
    if ((threadIdx.x & 63) == 0) sm[threadIdx.x >> 6] = s;
    __syncthreads();
    if (threadIdx.x == 0) {
        float tot = 0.f;
#pragma unroll
        for (int w = 0; w < 16; ++w) tot += sm[w];
        out[0] = tot * (1.0f / Bn);
    }
}

extern "C" void kernel_launch(void* const* d_in, const int* in_sizes, int n_in,
                              void* d_out, int out_size, void* d_ws, size_t ws_size,
                              hipStream_t stream)
{
    const float* x = (const float*)d_in[0];
    char* ws = (char*)d_ws;
    // workspace layout (bytes):
    uint8_t*  a_f8    = (uint8_t*)(ws + 0);          // 4 MB
    uint8_t*  p_f8    = (uint8_t*)(ws + 4194304);    // 4 MB
    float*    rnA     = (float*)(ws + 8388608);      // 32 KB
    float*    rnP     = (float*)(ws + 8421376);      // 32 KB
    float*    cterm   = (float*)(ws + 8454144);      // 32 KB
    float*    pval    = (float*)(ws + 8486912);      // 2 MB
    int*      pidx    = (int*)(ws + 10584064);       // 2 MB
    float*    rowloss = (float*)(ws + 12681216);     // 32 KB (total ~12.7 MB)
    float*    out     = (float*)d_out;

    k_normalize<<<4096, 256, 0, stream>>>(x, a_f8, p_f8, rnA, rnP, cterm);
    k_gemm_argmax<<<dim3(NCT, Bn / BM), 256, 0, stream>>>(a_f8, p_f8, cterm, pval, pidx);
    k_rowloss<<<2048, 256, 0, stream>>>(x, rnA, rnP, pval, pidx, rowloss);
    k_final<<<1, 1024, 0, stream>>>(rowloss, out);
}

// Round 10
// 229.899 us; speedup vs baseline: 1.2443x; 1.2443x over previous
//
#include <hip/hip_runtime.h>
#include <stdint.h>
#include <math.h>

// Problem constants (B=8192 rows, D=512 features)
#define Bn 8192
#define Dn 512
#define EPSN 1e-12f
#define EPSP 1e-6f
#define MARG 0.3f

// GEMM (byte-identical to R8's measured-best: 116-118us across 3 rounds):
// block 128x128, 4 waves 2x2, wave tile 64x64, BK=32, XOR-swizzled
// global_load_lds dbuf, __launch_bounds__(256,4) -> 4 blocks/CU (64 AGPR +
// 64 VGPR = 128 = exactly 4 waves/SIMD; 5 is register-infeasible).
// Session ledger: occ lever exhausted (R2/R6), B-out-of-LDS loses (R4/R7),
// fp8 mfma_scale spills to scratch (R9: 559 MB WRITE_SIZE), single-address
// atomicAdd +100us (R5). R10 trims the ~69us tail: pos-dist fused into
// k_normalize, k_final folded into k_rowloss (last-block ticket).
#define BM 128
#define BN 128
#define BK 32
#define KT (Dn / BK)    // 16 k-iterations
#define NCT (Bn / BN)   // 64 column tiles
#define RL_BLOCKS 2048  // k_rowloss grid (4 rows/block)

typedef short bf16x8 __attribute__((ext_vector_type(8)));  // 8 bf16 (4 VGPRs)
typedef float f32x4  __attribute__((ext_vector_type(4)));

__device__ __forceinline__ uint16_t f2bf(float f) {
    union { float f; uint32_t u; } c; c.f = f;
    uint32_t r = (c.u + 0x7fffu + ((c.u >> 16) & 1u)) >> 16;  // RNE
    return (uint16_t)r;
}

// async global->LDS, 16B per lane; LDS dest is wave-uniform base + lane*16
__device__ __forceinline__ void async16(const void* g, void* l) {
    __builtin_amdgcn_global_load_lds(
        (const __attribute__((address_space(1))) void*)g,
        (__attribute__((address_space(3))) void*)l,
        16, 0, 0);
}

// ---------------------------------------------------------------------------
// K1: one wave per row pair (a_i, p_i): L2-normalize both -> bf16 rows,
// inverse norms, column term c[j] = -sp2[j] + 2*eps*sp[j], and the exact
// fp32 positive distance pos2[i] = sum((a/||a|| - p/||p|| + eps)^2).
// Also zeroes the k_rowloss completion counter.
// ---------------------------------------------------------------------------
__global__ __launch_bounds__(256) void k_normalize(
    const float* __restrict__ x,
    uint16_t* __restrict__ a_bf, uint16_t* __restrict__ p_bf,
    float* __restrict__ rnA, float* __restrict__ rnP,
    float* __restrict__ cterm, float* __restrict__ rowpos,
    int* __restrict__ donecnt)
{
    if (blockIdx.x == 0 && threadIdx.x == 0) *donecnt = 0;

    const int wave = threadIdx.x >> 6;
    const int lane = threadIdx.x & 63;
    const int i = blockIdx.x * 4 + wave;   // 0..8191

    const float* srcA = x + (size_t)i * (2 * Dn) + lane * 8;
    const float* srcP = srcA + Dn;
    float4 a0 = ((const float4*)srcA)[0];
    float4 a1 = ((const float4*)srcA)[1];
    float4 p0 = ((const float4*)srcP)[0];
    float4 p1 = ((const float4*)srcP)[1];
    float va[8] = {a0.x, a0.y, a0.z, a0.w, a1.x, a1.y, a1.z, a1.w};
    float vp[8] = {p0.x, p0.y, p0.z, p0.w, p1.x, p1.y, p1.z, p1.w};

    float ssa = 0.f, ssp = 0.f;
#pragma unroll
    for (int j = 0; j < 8; ++j) { ssa += va[j] * va[j]; ssp += vp[j] * vp[j]; }
#pragma unroll
    for (int m = 1; m < 64; m <<= 1) {
        ssa += __shfl_xor(ssa, m);
        ssp += __shfl_xor(ssp, m);
    }
    const float sa = 1.0f / fmaxf(sqrtf(ssa), EPSN);
    const float sp = 1.0f / fmaxf(sqrtf(ssp), EPSN);

    float oa[8], op[8], s1 = 0.f, s2 = 0.f, pos = 0.f;
#pragma unroll
    for (int j = 0; j < 8; ++j) {
        oa[j] = va[j] * sa;
        op[j] = vp[j] * sp;
        s1 += op[j]; s2 += op[j] * op[j];
        const float u = oa[j] - op[j] + EPSP;
        pos += u * u;
    }

    bf16x8 ba, bp;
#pragma unroll
    for (int j = 0; j < 8; ++j) { ba[j] = (short)f2bf(oa[j]); bp[j] = (short)f2bf(op[j]); }
    *(bf16x8*)(a_bf + (size_t)i * Dn + lane * 8) = ba;
    *(bf16x8*)(p_bf + (size_t)i * Dn + lane * 8) = bp;

#pragma unroll
    for (int m = 1; m < 64; m <<= 1) {
        s1 += __shfl_xor(s1, m);
        s2 += __shfl_xor(s2, m);
        pos += __shfl_xor(pos, m);
    }
    if (lane == 0) {
        rnA[i] = sa;
        rnP[i] = sp;
        cterm[i] = -s2 + 2.0f * EPSP * s1;
        rowpos[i] = pos;
    }
}

// ---------------------------------------------------------------------------
// K2: bf16 MFMA GEMM (a_n @ p_n^T) + fused per-row argmax over the 128-col
// tile. Byte-identical to R8 (measured 116-118us, MfmaUtil 24, 0 conflicts).
// ---------------------------------------------------------------------------
__global__ __launch_bounds__(256, 4) void k_gemm_argmax(
    const uint16_t* __restrict__ a_bf, const uint16_t* __restrict__ p_bf,
    const float* __restrict__ cterm,
    float* __restrict__ pval, int* __restrict__ pidx)
{
    __shared__ uint16_t As[2][BM * BK];   // 2 x 8 KB
    __shared__ uint16_t Bs[2][BN * BK];   // 2 x 8 KB
    __shared__ float rv[2][BM];
    __shared__ int   ri[2][BM];

    const int t = threadIdx.x;
    const int wave = t >> 6;
    const int lane = t & 63;
    const int rowBase = blockIdx.y * BM;
    const int colBase = blockIdx.x * BN;

    const int q = lane >> 4;       // 0..3  (k-chunk)
    const int m16 = lane & 15;     // 0..15
    const int waveRow = (wave >> 1) * 64;
    const int waveCol = (wave & 1) * 64;

    // staging pointers, hoisted (chunk c -> row c>>2, slot c&3 holds global
    // k-chunk (c&3)^((row>>1)&3))
    const int r0 = t >> 2;
    const int g0 = (t & 3) ^ ((r0 >> 1) & 3);
    const int r1 = (256 + t) >> 2;
    const int g1 = ((256 + t) & 3) ^ ((r1 >> 1) & 3);
    const uint16_t* gA0 = a_bf + (size_t)(rowBase + r0) * Dn + g0 * 8;
    const uint16_t* gA1 = a_bf + (size_t)(rowBase + r1) * Dn + g1 * 8;
    const uint16_t* gB0 = p_bf + (size_t)(colBase + r0) * Dn + g0 * 8;
    const uint16_t* gB1 = p_bf + (size_t)(colBase + r1) * Dn + g1 * 8;
    const int ldsC0 = (wave * 64) * 8;           // wave-uniform LDS dest bases
    const int ldsC1 = (256 + wave * 64) * 8;

    // fragment LDS read bases: slot = q ^ ((m16>>1)&3) for ALL mt/nt
    const int s0 = q ^ ((m16 >> 1) & 3);
    const int aBase = (waveRow + m16) * BK + s0 * 8;
    const int bBase = (waveCol + m16) * BK + s0 * 8;

    f32x4 acc[4][4];
#pragma unroll
    for (int a = 0; a < 4; ++a)
#pragma unroll
        for (int b = 0; b < 4; ++b) acc[a][b] = (f32x4){0.f, 0.f, 0.f, 0.f};

    auto stage = [&](int buf, int ke) {
        async16(gA0 + ke, &As[buf][ldsC0]);
        async16(gA1 + ke, &As[buf][ldsC1]);
        async16(gB0 + ke, &Bs[buf][ldsC0]);
        async16(gB1 + ke, &Bs[buf][ldsC1]);
    };

    stage(0, 0);
#pragma unroll
    for (int kt = 0; kt < KT; ++kt) {
        const int cur = kt & 1;
        __syncthreads();                 // tile kt resident; prior buf reads done
        if (kt + 1 < KT) stage(cur ^ 1, (kt + 1) * BK);  // drains at NEXT barrier

        const uint16_t* pa = &As[cur][aBase];
        const uint16_t* pb = &Bs[cur][bBase];
        bf16x8 af[4], bfr[4];
#pragma unroll
        for (int mt = 0; mt < 4; ++mt)
            af[mt] = *(const bf16x8*)(pa + mt * 16 * BK);
#pragma unroll
        for (int nt = 0; nt < 4; ++nt)
            bfr[nt] = *(const bf16x8*)(pb + nt * 16 * BK);
#pragma unroll
        for (int mt = 0; mt < 4; ++mt)
#pragma unroll
            for (int nt = 0; nt < 4; ++nt)
                acc[mt][nt] = __builtin_amdgcn_mfma_f32_16x16x32_bf16(
                    af[mt], bfr[nt], acc[mt][nt], 0, 0, 0);
    }

    // epilogue: score = 2*dot + c[j]; mask diagonal; per-row argmax
    float cv[4];
#pragma unroll
    for (int nt = 0; nt < 4; ++nt)
        cv[nt] = cterm[colBase + waveCol + nt * 16 + m16];

#pragma unroll
    for (int mt = 0; mt < 4; ++mt) {
#pragma unroll
        for (int v = 0; v < 4; ++v) {
            const int lr = waveRow + mt * 16 + q * 4 + v;   // C/D row = quad*4+reg
            const int gi = rowBase + lr;
            float best = -INFINITY;
            int bidx = 0x7fffffff;
#pragma unroll
            for (int nt = 0; nt < 4; ++nt) {
                const int gj = colBase + waveCol + nt * 16 + m16;  // col = lane&15
                float sc = 2.0f * acc[mt][nt][v] + cv[nt];
                if (gj == gi) sc = -INFINITY;
                if (sc > best || (sc == best && gj < bidx)) { best = sc; bidx = gj; }
            }
#pragma unroll
            for (int msk = 1; msk < 16; msk <<= 1) {       // reduce over 16 cols
                float ob = __shfl_xor(best, msk);
                int oi = __shfl_xor(bidx, msk);
                if (ob > best || (ob == best && oi < bidx)) { best = ob; bidx = oi; }
            }
            if (m16 == 0) { rv[wave & 1][lr] = best; ri[wave & 1][lr] = bidx; }
        }
    }
    __syncthreads();
    if (t < BM) {
        float b0 = rv[0][t]; int i0 = ri[0][t];
        float b1 = rv[1][t]; int i1 = ri[1][t];
        if (b1 > b0 || (b1 == b0 && i1 < i0)) { b0 = b1; i0 = i1; }
        const size_t o = (size_t)(rowBase + t) * NCT + blockIdx.x;
        pval[o] = b0;
        pidx[o] = i0;
    }
}

// ---------------------------------------------------------------------------
// K3: reduce 64 partials -> negidx; neg distance in exact fp32 from x + the
// stored inverse norms; rowloss = relu(pos2 - neg2 + margin). Block-partial
// sums + last-block ticket finalize the mean (deterministic: fixed-order
// per-block sums, fixed-order final sum; only the counter is atomic).
// ---------------------------------------------------------------------------
__global__ __launch_bounds__(256) void k_rowloss(
    const float* __restrict__ x,
    const float* __restrict__ rnA, const float* __restrict__ rnP,
    const float* __restrict__ pval, const int* __restrict__ pidx,
    const float* __restrict__ rowpos,
    float* __restrict__ partial, int* __restrict__ donecnt,
    float* __restrict__ out)
{
    __shared__ float sm[4];
    const int wave = threadIdx.x >> 6;
    const int lane = threadIdx.x & 63;
    const int i = blockIdx.x * 4 + wave;

    float best = pval[(size_t)i * NCT + lane];
    int bidx = pidx[(size_t)i * NCT + lane];
#pragma unroll
    for (int msk = 1; msk < 64; msk <<= 1) {
        float ob = __shfl_xor(best, msk);
        int oi = __shfl_xor(bidx, msk);
        if (ob > best || (ob == best && oi < bidx)) { best = ob; bidx = oi; }
    }

    const float ra = rnA[i];
    const float rn = rnP[bidx];
    const float4* av = (const float4*)(x + (size_t)i * (2 * Dn));
    const float4* nv = (const float4*)(x + (size_t)bidx * (2 * Dn) + Dn);
    float ng = 0.f;
#pragma unroll
    for (int c = 0; c < 2; ++c) {
        const int idx = lane + c * 64;
        float4 a4 = av[idx], n4 = nv[idx];
        float u;
        u = a4.x * ra - n4.x * rn + EPSP; ng += u * u;
        u = a4.y * ra - n4.y * rn + EPSP; ng += u * u;
        u = a4.z * ra - n4.z * rn + EPSP; ng += u * u;
        u = a4.w * ra - n4.w * rn + EPSP; ng += u * u;
    }
#pragma unroll
    for (int msk = 1; msk < 64; msk <<= 1) ng += __shfl_xor(ng, msk);

    if (lane == 0)
        sm[wave] = fmaxf(rowpos[i] - ng + MARG, 0.f);
    __syncthreads();
    if (threadIdx.x == 0)
        partial[blockIdx.x] = (sm[0] + sm[1] + sm[2] + sm[3]) * (1.0f / Bn);

    // last-block ticket: the final arriving block sums all partials.
    __syncthreads();
    __shared__ int amLast;
    if (threadIdx.x == 0) {
        __threadfence();                       // publish partial[] before ticket
        amLast = (atomicAdd(donecnt, 1) == RL_BLOCKS - 1);
    }
    __syncthreads();
    if (amLast) {
        __threadfence();                       // see all partials
        float s = 0.f;
        for (int k = threadIdx.x; k < RL_BLOCKS; k += 256) s += partial[k];
#pragma unroll
        for (int msk = 1; msk < 64; msk <<= 1) s += __shfl_xor(s, msk);
        __shared__ float fm[4];
        if (lane == 0) fm[wave] = s;
        __syncthreads();
        if (threadIdx.x == 0) out[0] = fm[0] + fm[1] + fm[2] + fm[3];
    }
}

extern "C" void kernel_launch(void* const* d_in, const int* in_sizes, int n_in,
                              void* d_out, int out_size, void* d_ws, size_t ws_size,
                              hipStream_t stream)
{
    const float* x = (const float*)d_in[0];
    char* ws = (char*)d_ws;
    // workspace layout (bytes):
    uint16_t* a_bf    = (uint16_t*)(ws + 0);         // 8 MB
    uint16_t* p_bf    = (uint16_t*)(ws + 8388608);   // 8 MB
    float*    rnA     = (float*)(ws + 16777216);     // 32 KB
    float*    rnP     = (float*)(ws + 16809984);     // 32 KB
    float*    cterm   = (float*)(ws + 16842752);     // 32 KB
    float*    pval    = (float*)(ws + 16875520);     // 2 MB
    int*      pidx    = (int*)(ws + 18972672);       // 2 MB
    float*    rowpos  = (float*)(ws + 21069824);     // 32 KB
    float*    partial = (float*)(ws + 21102592);     // 8 KB
    int*      donecnt = (int*)(ws + 21110784);       // 4 B  (total ~21.1 MB)
    float*    out     = (float*)d_out;

    k_normalize<<<2048, 256, 0, stream>>>(x, a_bf, p_bf, rnA, rnP, cterm,
                                          rowpos, donecnt);
    k_gemm_argmax<<<dim3(NCT, Bn / BM), 256, 0, stream>>>(a_bf, p_bf, cterm,
                                                          pval, pidx);
    k_rowloss<<<RL_BLOCKS, 256, 0, stream>>>(x, rnA, rnP, pval, pidx, rowpos,
                                             partial, donecnt, out);
}

// Round 11
// 160.042 us; speedup vs baseline: 1.7874x; 1.4365x over previous
//
#include <hip/hip_runtime.h>
#include <stdint.h>
#include <math.h>

// Problem constants (B=8192 rows, D=512 features)
#define Bn 8192
#define Dn 512
#define EPSN 1e-12f
#define EPSP 1e-6f
#define MARG 0.3f

// R11: GEMM in int8 via mfma_i32_16x16x64_i8. KT halves 16->8 at R8's EXACT
// register geometry (4-reg A/B frags, 4x4 x 4-reg acc = 64 AGPR; ~64 VGPR ->
// 4 blocks/CU) and EXACT LDS byte layout (64 B/row-tile, 4x16B chunks, same
// XOR swizzle -> same verified-0-conflict addresses). Avoids R9-fp8's spill
// cause (8-reg operands + f32x16 acc -> 559 MB scratch traffic).
// Rows quantized at scale 256 (|elem| max ~0.24 << 127/256=0.496); integer
// dot is exact; score = 2*idot/65536 + cterm. pos/neg distances exact fp32.
// Tail = R8's clean 3-kernel form (R10's ticket atomics/fences regressed).
#define BM 128
#define BN 128
#define BKB 64          // k elements (=bytes) per tile
#define KT (Dn / BKB)   // 8 k-iterations
#define NCT (Bn / BN)   // 64 column tiles
#define QS 256.0f
#define ISQ (2.0f / 65536.0f)

typedef int   int4v __attribute__((ext_vector_type(4)));
typedef float f32x4 __attribute__((ext_vector_type(4)));

// async global->LDS, 16B per lane; LDS dest is wave-uniform base + lane*16
__device__ __forceinline__ void async16(const void* g, void* l) {
    __builtin_amdgcn_global_load_lds(
        (const __attribute__((address_space(1))) void*)g,
        (__attribute__((address_space(3))) void*)l,
        16, 0, 0);
}

// ---------------------------------------------------------------------------
// K1: per-row L2 normalize -> i8 rows (x256, RNE, clamp +-127), inverse
// norms, column term c[j] = -sp2[j] + 2*eps*sp[j] (exact fp32).
// One wave per 512-float row, 16384 rows.
// ---------------------------------------------------------------------------
__global__ __launch_bounds__(256) void k_normalize(
    const float* __restrict__ x,
    uint8_t* __restrict__ a_i8, uint8_t* __restrict__ p_i8,
    float* __restrict__ rnA, float* __restrict__ rnP,
    float* __restrict__ cterm)
{
    const int wave = threadIdx.x >> 6;
    const int lane = threadIdx.x & 63;
    const int r = blockIdx.x * 4 + wave;   // 0..16383
    const int i = r >> 1;
    const int which = r & 1;               // 0 = a-row, 1 = p-row

    const float* src = x + (size_t)i * (2 * Dn) + (size_t)which * Dn + lane * 8;
    float4 lo = ((const float4*)src)[0];
    float4 hi = ((const float4*)src)[1];
    float v[8] = {lo.x, lo.y, lo.z, lo.w, hi.x, hi.y, hi.z, hi.w};

    float ss = 0.f;
#pragma unroll
    for (int j = 0; j < 8; ++j) ss += v[j] * v[j];
#pragma unroll
    for (int m = 1; m < 64; m <<= 1) ss += __shfl_xor(ss, m);
    const float scale = 1.0f / fmaxf(sqrtf(ss), EPSN);

    float o[8], s1 = 0.f, s2 = 0.f;
#pragma unroll
    for (int j = 0; j < 8; ++j) { o[j] = v[j] * scale; s1 += o[j]; s2 += o[j] * o[j]; }

    uint64_t pk = 0;
#pragma unroll
    for (int j = 0; j < 8; ++j) {
        int q = (int)rintf(o[j] * QS);
        q = q > 127 ? 127 : (q < -127 ? -127 : q);
        pk |= (uint64_t)(uint8_t)q << (8 * j);
    }
    *(uint64_t*)((which ? p_i8 : a_i8) + (size_t)i * Dn + lane * 8) = pk;

    if (which) {
#pragma unroll
        for (int m = 1; m < 64; m <<= 1) { s1 += __shfl_xor(s1, m); s2 += __shfl_xor(s2, m); }
        if (lane == 0) { cterm[i] = -s2 + 2.0f * EPSP * s1; rnP[i] = scale; }
    } else {
        if (lane == 0) rnA[i] = scale;
    }
}

// ---------------------------------------------------------------------------
// K2: i8 MFMA GEMM (a_n @ p_n^T, x65536 scaled, exact int accumulate) +
// fused per-row argmax. 128x128 block, 4 waves 2x2, wave tile 64x64 =
// 4x4 mfma 16x16x64. A/B frag: m(n)=lane&15, k=(lane>>4)*16+j (16 contig B
// = one LDS chunk/lane - same addresses as R8's verified pattern).
// C/D: col=lane&15, row=(lane>>4)*4+reg (dtype-independent, guide-verified).
// ---------------------------------------------------------------------------
__global__ __launch_bounds__(256, 4) void k_gemm_argmax(
    const uint8_t* __restrict__ a_i8, const uint8_t* __restrict__ p_i8,
    const float* __restrict__ cterm,
    float* __restrict__ pval, int* __restrict__ pidx)
{
    __shared__ uint8_t As[2][BM * BKB];   // 2 x 8 KB
    __shared__ uint8_t Bs[2][BN * BKB];   // 2 x 8 KB
    __shared__ float rv[2][BM];
    __shared__ int   ri[2][BM];

    const int t = threadIdx.x;
    const int wave = t >> 6;
    const int lane = t & 63;
    const int rowBase = blockIdx.y * BM;
    const int colBase = blockIdx.x * BN;

    const int q = lane >> 4;       // 0..3  (k-chunk)
    const int m16 = lane & 15;     // 0..15
    const int waveRow = (wave >> 1) * 64;
    const int waveCol = (wave & 1) * 64;

    // staging pointers, hoisted (chunk c -> row c>>2, slot c&3 holds global
    // k-chunk (c&3)^((row>>1)&3)); identical byte geometry to R8.
    const int r0 = t >> 2;
    const int g0 = (t & 3) ^ ((r0 >> 1) & 3);
    const int r1 = (256 + t) >> 2;
    const int g1 = ((256 + t) & 3) ^ ((r1 >> 1) & 3);
    const uint8_t* gA0 = a_i8 + (size_t)(rowBase + r0) * Dn + g0 * 16;
    const uint8_t* gA1 = a_i8 + (size_t)(rowBase + r1) * Dn + g1 * 16;
    const uint8_t* gB0 = p_i8 + (size_t)(colBase + r0) * Dn + g0 * 16;
    const uint8_t* gB1 = p_i8 + (size_t)(colBase + r1) * Dn + g1 * 16;
    const int ldsC0 = (wave * 64) * 16;          // bytes; HW adds lane*16
    const int ldsC1 = (256 + wave * 64) * 16;

    // fragment LDS read bases: slot = q ^ ((m16>>1)&3) for ALL mt/nt
    const int s0 = q ^ ((m16 >> 1) & 3);
    const int aBase = (waveRow + m16) * BKB + s0 * 16;   // bytes
    const int bBase = (waveCol + m16) * BKB + s0 * 16;

    int4v acc[4][4];
#pragma unroll
    for (int a = 0; a < 4; ++a)
#pragma unroll
        for (int b = 0; b < 4; ++b) acc[a][b] = (int4v){0, 0, 0, 0};

    auto stage = [&](int buf, int ke) {      // ke = byte offset kt*64
        async16(gA0 + ke, &As[buf][ldsC0]);
        async16(gA1 + ke, &As[buf][ldsC1]);
        async16(gB0 + ke, &Bs[buf][ldsC0]);
        async16(gB1 + ke, &Bs[buf][ldsC1]);
    };

    stage(0, 0);
#pragma unroll
    for (int kt = 0; kt < KT; ++kt) {
        const int cur = kt & 1;
        __syncthreads();                 // tile kt resident; prior buf reads done
        if (kt + 1 < KT) stage(cur ^ 1, (kt + 1) * BKB);  // drains at NEXT barrier

        const uint8_t* pa = &As[cur][aBase];
        const uint8_t* pb = &Bs[cur][bBase];
        int4v af[4], bfr[4];
#pragma unroll
        for (int mt = 0; mt < 4; ++mt)
            af[mt] = *(const int4v*)(pa + mt * 16 * BKB);
#pragma unroll
        for (int nt = 0; nt < 4; ++nt)
            bfr[nt] = *(const int4v*)(pb + nt * 16 * BKB);
#pragma unroll
        for (int mt = 0; mt < 4; ++mt)
#pragma unroll
            for (int nt = 0; nt < 4; ++nt)
                acc[mt][nt] = __builtin_amdgcn_mfma_i32_16x16x64_i8(
                    af[mt], bfr[nt], acc[mt][nt], 0, 0, 0);
    }

    // epilogue: score = 2*idot/65536 + c[j]; mask diagonal; per-row argmax
    float cv[4];
#pragma unroll
    for (int nt = 0; nt < 4; ++nt)
        cv[nt] = cterm[colBase + waveCol + nt * 16 + m16];

#pragma unroll
    for (int mt = 0; mt < 4; ++mt) {
#pragma unroll
        for (int v = 0; v < 4; ++v) {
            const int lr = waveRow + mt * 16 + q * 4 + v;   // C/D row = quad*4+reg
            const int gi = rowBase + lr;
            float best = -INFINITY;
            int bidx = 0x7fffffff;
#pragma unroll
            for (int nt = 0; nt < 4; ++nt) {
                const int gj = colBase + waveCol + nt * 16 + m16;  // col = lane&15
                float sc = ISQ * (float)acc[mt][nt][v] + cv[nt];
                if (gj == gi) sc = -INFINITY;
                if (sc > best || (sc == best && gj < bidx)) { best = sc; bidx = gj; }
            }
#pragma unroll
            for (int msk = 1; msk < 16; msk <<= 1) {       // reduce over 16 cols
                float ob = __shfl_xor(best, msk);
                int oi = __shfl_xor(bidx, msk);
                if (ob > best || (ob == best && oi < bidx)) { best = ob; bidx = oi; }
            }
            if (m16 == 0) { rv[wave & 1][lr] = best; ri[wave & 1][lr] = bidx; }
        }
    }
    __syncthreads();
    if (t < BM) {
        float b0 = rv[0][t]; int i0 = ri[0][t];
        float b1 = rv[1][t]; int i1 = ri[1][t];
        if (b1 > b0 || (b1 == b0 && i1 < i0)) { b0 = b1; i0 = i1; }
        const size_t o = (size_t)(rowBase + t) * NCT + blockIdx.x;
        pval[o] = b0;
        pidx[o] = i0;
    }
}

// ---------------------------------------------------------------------------
// K3: reduce 64 partials -> negidx; recompute normalized rows from x + stored
// inverse norms; pos/neg distances fp32 per reference; relu -> rowloss.
// One wave per row. (Non-atomic: single-address atomics cost ~100us, R5/R10.)
// ---------------------------------------------------------------------------
__global__ __launch_bounds__(256) void k_rowloss(
    const float* __restrict__ x,
    const float* __restrict__ rnA, const float* __restrict__ rnP,
    const float* __restrict__ pval, const int* __restrict__ pidx,
    float* __restrict__ rowloss)
{
    const int wave = threadIdx.x >> 6;
    const int lane = threadIdx.x & 63;
    const int i = blockIdx.x * 4 + wave;

    float best = pval[(size_t)i * NCT + lane];
    int bidx = pidx[(size_t)i * NCT + lane];
#pragma unroll
    for (int msk = 1; msk < 64; msk <<= 1) {
        float ob = __shfl_xor(best, msk);
        int oi = __shfl_xor(bidx, msk);
        if (ob > best || (ob == best && oi < bidx)) { best = ob; bidx = oi; }
    }

    const float ra = rnA[i];
    const float rp = rnP[i];
    const float rn = rnP[bidx];
    const float4* av = (const float4*)(x + (size_t)i * (2 * Dn));
    const float4* pv = (const float4*)(x + (size_t)i * (2 * Dn) + Dn);
    const float4* nv = (const float4*)(x + (size_t)bidx * (2 * Dn) + Dn);
    float pos = 0.f, ng = 0.f;
#pragma unroll
    for (int c = 0; c < 2; ++c) {
        const int idx = lane + c * 64;
        float4 a4 = av[idx], p4 = pv[idx], n4 = nv[idx];
        float u;
        u = a4.x * ra - p4.x * rp + EPSP; pos += u * u;
        u = a4.y * ra - p4.y * rp + EPSP; pos += u * u;
        u = a4.z * ra - p4.z * rp + EPSP; pos += u * u;
        u = a4.w * ra - p4.w * rp + EPSP; pos += u * u;
        u = a4.x * ra - n4.x * rn + EPSP; ng += u * u;
        u = a4.y * ra - n4.y * rn + EPSP; ng += u * u;
        u = a4.z * ra - n4.z * rn + EPSP; ng += u * u;
        u = a4.w * ra - n4.w * rn + EPSP; ng += u * u;
    }
#pragma unroll
    for (int msk = 1; msk < 64; msk <<= 1) {
        pos += __shfl_xor(pos, msk);
        ng += __shfl_xor(ng, msk);
    }
    if (lane == 0) rowloss[i] = fmaxf(pos - ng + MARG, 0.f);
}

// ---------------------------------------------------------------------------
// K4: mean over 8192 row losses -> scalar out (deterministic)
// ---------------------------------------------------------------------------
__global__ __launch_bounds__(1024) void k_final(
    const float* __restrict__ rowloss, float* __restrict__ out)
{
    __shared__ float sm[16];
    float s = 0.f;
    for (int k = threadIdx.x; k < Bn; k += 1024) s += rowloss[k];
#pragma unroll
    for (int msk = 1; msk < 64; msk <<= 1) s += __shfl_xor(s, msk);
    if ((threadIdx.x & 63) == 0) sm[threadIdx.x >> 6] = s;
    __syncthreads();
    if (threadIdx.x == 0) {
        float tot = 0.f;
#pragma unroll
        for (int w = 0; w < 16; ++w) tot += sm[w];
        out[0] = tot * (1.0f / Bn);
    }
}

extern "C" void kernel_launch(void* const* d_in, const int* in_sizes, int n_in,
                              void* d_out, int out_size, void* d_ws, size_t ws_size,
                              hipStream_t stream)
{
    const float* x = (const float*)d_in[0];
    char* ws = (char*)d_ws;
    // workspace layout (bytes):
    uint8_t*  a_i8    = (uint8_t*)(ws + 0);          // 4 MB
    uint8_t*  p_i8    = (uint8_t*)(ws + 4194304);    // 4 MB
    float*    rnA     = (float*)(ws + 8388608);      // 32 KB
    float*    rnP     = (float*)(ws + 8421376);      // 32 KB
    float*    cterm   = (float*)(ws + 8454144);      // 32 KB
    float*    pval    = (float*)(ws + 8486912);      // 2 MB
    int*      pidx    = (int*)(ws + 10584064);       // 2 MB
    float*    rowloss = (float*)(ws + 12681216);     // 32 KB (total ~12.7 MB)
    float*    out     = (float*)d_out;

    k_normalize<<<4096, 256, 0, stream>>>(x, a_i8, p_i8, rnA, rnP, cterm);
    k_gemm_argmax<<<dim3(NCT, Bn / BM), 256, 0, stream>>>(a_i8, p_i8, cterm,
                                                          pval, pidx);
    k_rowloss<<<2048, 256, 0, stream>>>(x, rnA, rnP, pval, pidx, rowloss);
    k_final<<<1, 1024, 0, stream>>>(rowloss, out);
}

// Round 13
// 157.366 us; speedup vs baseline: 1.8178x; 1.0170x over previous
//
#include <hip/hip_runtime.h>
#include <stdint.h>
#include <math.h>

// Problem constants (B=8192 rows, D=512 features)
#define Bn 8192
#define Dn 512
#define EPSN 1e-12f
#define EPSP 1e-6f
#define MARG 0.3f

// R13 = R11's verbatim i8 GEMM (84us, MfmaUtil 16, 0 conflicts, absmax 0.0)
// + tail micro-fusion: k_normalize handles the (a,p) pair in one wave and
// precomputes exact fp32 pos^2; k_rowloss drops its p-row read (-16 MB).
// Plain stream-ordered kernels only - session ledger on tail structures:
// single-address atomicAdd +100us (R5), ticket+fence +20us (R10),
// hipLaunchCooperativeKernel silently no-ops under graph capture (R12).
// GEMM ledger: occupancy lever exhausted (R2/R5/R6), B-out-of-LDS loses
// (R4/R7), fp8 mfma_scale spills (R9), i8 2xK wins at R8's exact reg/LDS
// geometry (R11).
#define BM 128
#define BN 128
#define BKB 64          // k elements (=bytes) per tile
#define KT (Dn / BKB)   // 8 k-iterations
#define NCT (Bn / BN)   // 64 column tiles
#define QS 256.0f
#define ISQ (2.0f / 65536.0f)

typedef int   int4v __attribute__((ext_vector_type(4)));
typedef float f32x4 __attribute__((ext_vector_type(4)));

// async global->LDS, 16B per lane; LDS dest is wave-uniform base + lane*16
__device__ __forceinline__ void async16(const void* g, void* l) {
    __builtin_amdgcn_global_load_lds(
        (const __attribute__((address_space(1))) void*)g,
        (__attribute__((address_space(3))) void*)l,
        16, 0, 0);
}

// ---------------------------------------------------------------------------
// K1: one wave per row pair (a_i, p_i): L2-normalize both -> i8 rows (x256,
// RNE, clamp +-127), inverse norms, column term c[j] = -sp2[j] + 2*eps*sp[j],
// and exact fp32 pos2[i] = sum((a/||a|| - p/||p|| + eps)^2). 2048 blocks.
// ---------------------------------------------------------------------------
__global__ __launch_bounds__(256) void k_normalize(
    const float* __restrict__ x,
    uint8_t* __restrict__ a_i8, uint8_t* __restrict__ p_i8,
    float* __restrict__ rnA, float* __restrict__ rnP,
    float* __restrict__ cterm, float* __restrict__ rowpos)
{
    const int wave = threadIdx.x >> 6;
    const int lane = threadIdx.x & 63;
    const int i = blockIdx.x * 4 + wave;   // 0..8191

    const float* srcA = x + (size_t)i * (2 * Dn) + lane * 8;
    const float* srcP = srcA + Dn;
    float4 a0 = ((const float4*)srcA)[0];
    float4 a1 = ((const float4*)srcA)[1];
    float4 p0 = ((const float4*)srcP)[0];
    float4 p1 = ((const float4*)srcP)[1];
    float va[8] = {a0.x, a0.y, a0.z, a0.w, a1.x, a1.y, a1.z, a1.w};
    float vp[8] = {p0.x, p0.y, p0.z, p0.w, p1.x, p1.y, p1.z, p1.w};

    float ssa = 0.f, ssp = 0.f;
#pragma unroll
    for (int j = 0; j < 8; ++j) { ssa += va[j] * va[j]; ssp += vp[j] * vp[j]; }
#pragma unroll
    for (int m = 1; m < 64; m <<= 1) {
        ssa += __shfl_xor(ssa, m);
        ssp += __shfl_xor(ssp, m);
    }
    const float sa = 1.0f / fmaxf(sqrtf(ssa), EPSN);
    const float sp = 1.0f / fmaxf(sqrtf(ssp), EPSN);

    float oa[8], op[8], s1 = 0.f, s2 = 0.f, pos = 0.f;
#pragma unroll
    for (int j = 0; j < 8; ++j) {
        oa[j] = va[j] * sa;
        op[j] = vp[j] * sp;
        s1 += op[j]; s2 += op[j] * op[j];
        const float u = oa[j] - op[j] + EPSP;
        pos += u * u;
    }

    uint64_t pka = 0, pkp = 0;
#pragma unroll
    for (int j = 0; j < 8; ++j) {
        int qa = (int)rintf(oa[j] * QS);
        int qp = (int)rintf(op[j] * QS);
        qa = qa > 127 ? 127 : (qa < -127 ? -127 : qa);
        qp = qp > 127 ? 127 : (qp < -127 ? -127 : qp);
        pka |= (uint64_t)(uint8_t)qa << (8 * j);
        pkp |= (uint64_t)(uint8_t)qp << (8 * j);
    }
    *(uint64_t*)(a_i8 + (size_t)i * Dn + lane * 8) = pka;
    *(uint64_t*)(p_i8 + (size_t)i * Dn + lane * 8) = pkp;

#pragma unroll
    for (int m = 1; m < 64; m <<= 1) {
        s1 += __shfl_xor(s1, m);
        s2 += __shfl_xor(s2, m);
        pos += __shfl_xor(pos, m);
    }
    if (lane == 0) {
        rnA[i] = sa;
        rnP[i] = sp;
        cterm[i] = -s2 + 2.0f * EPSP * s1;
        rowpos[i] = pos;
    }
}

// ---------------------------------------------------------------------------
// K2: i8 MFMA GEMM (a_n @ p_n^T, x65536 scaled, exact int accumulate) +
// fused per-row argmax. Byte-identical to R11 (measured 84us).
// ---------------------------------------------------------------------------
__global__ __launch_bounds__(256, 4) void k_gemm_argmax(
    const uint8_t* __restrict__ a_i8, const uint8_t* __restrict__ p_i8,
    const float* __restrict__ cterm,
    float* __restrict__ pval, int* __restrict__ pidx)
{
    __shared__ uint8_t As[2][BM * BKB];   // 2 x 8 KB
    __shared__ uint8_t Bs[2][BN * BKB];   // 2 x 8 KB
    __shared__ float rv[2][BM];
    __shared__ int   ri[2][BM];

    const int t = threadIdx.x;
    const int wave = t >> 6;
    const int lane = t & 63;
    const int rowBase = blockIdx.y * BM;
    const int colBase = blockIdx.x * BN;

    const int q = lane >> 4;       // 0..3  (k-chunk)
    const int m16 = lane & 15;     // 0..15
    const int waveRow = (wave >> 1) * 64;
    const int waveCol = (wave & 1) * 64;

    // staging pointers, hoisted (chunk c -> row c>>2, slot c&3 holds global
    // k-chunk (c&3)^((row>>1)&3))
    const int r0 = t >> 2;
    const int g0 = (t & 3) ^ ((r0 >> 1) & 3);
    const int r1 = (256 + t) >> 2;
    const int g1 = ((256 + t) & 3) ^ ((r1 >> 1) & 3);
    const uint8_t* gA0 = a_i8 + (size_t)(rowBase + r0) * Dn + g0 * 16;
    const uint8_t* gA1 = a_i8 + (size_t)(rowBase + r1) * Dn + g1 * 16;
    const uint8_t* gB0 = p_i8 + (size_t)(colBase + r0) * Dn + g0 * 16;
    const uint8_t* gB1 = p_i8 + (size_t)(colBase + r1) * Dn + g1 * 16;
    const int ldsC0 = (wave * 64) * 16;          // bytes; HW adds lane*16
    const int ldsC1 = (256 + wave * 64) * 16;

    // fragment LDS read bases: slot = q ^ ((m16>>1)&3) for ALL mt/nt
    const int s0 = q ^ ((m16 >> 1) & 3);
    const int aBase = (waveRow + m16) * BKB + s0 * 16;   // bytes
    const int bBase = (waveCol + m16) * BKB + s0 * 16;

    int4v acc[4][4];
#pragma unroll
    for (int a = 0; a < 4; ++a)
#pragma unroll
        for (int b = 0; b < 4; ++b) acc[a][b] = (int4v){0, 0, 0, 0};

    auto stage = [&](int buf, int ke) {      // ke = byte offset kt*64
        async16(gA0 + ke, &As[buf][ldsC0]);
        async16(gA1 + ke, &As[buf][ldsC1]);
        async16(gB0 + ke, &Bs[buf][ldsC0]);
        async16(gB1 + ke, &Bs[buf][ldsC1]);
    };

    stage(0, 0);
#pragma unroll
    for (int kt = 0; kt < KT; ++kt) {
        const int cur = kt & 1;
        __syncthreads();                 // tile kt resident; prior buf reads done
        if (kt + 1 < KT) stage(cur ^ 1, (kt + 1) * BKB);  // drains at NEXT barrier

        const uint8_t* pa = &As[cur][aBase];
        const uint8_t* pb = &Bs[cur][bBase];
        int4v af[4], bfr[4];
#pragma unroll
        for (int mt = 0; mt < 4; ++mt)
            af[mt] = *(const int4v*)(pa + mt * 16 * BKB);
#pragma unroll
        for (int nt = 0; nt < 4; ++nt)
            bfr[nt] = *(const int4v*)(pb + nt * 16 * BKB);
#pragma unroll
        for (int mt = 0; mt < 4; ++mt)
#pragma unroll
            for (int nt = 0; nt < 4; ++nt)
                acc[mt][nt] = __builtin_amdgcn_mfma_i32_16x16x64_i8(
                    af[mt], bfr[nt], acc[mt][nt], 0, 0, 0);
    }

    // epilogue: score = 2*idot/65536 + c[j]; mask diagonal; per-row argmax
    float cv[4];
#pragma unroll
    for (int nt = 0; nt < 4; ++nt)
        cv[nt] = cterm[colBase + waveCol + nt * 16 + m16];

#pragma unroll
    for (int mt = 0; mt < 4; ++mt) {
#pragma unroll
        for (int v = 0; v < 4; ++v) {
            const int lr = waveRow + mt * 16 + q * 4 + v;   // C/D row = quad*4+reg
            const int gi = rowBase + lr;
            float best = -INFINITY;
            int bidx = 0x7fffffff;
#pragma unroll
            for (int nt = 0; nt < 4; ++nt) {
                const int gj = colBase + waveCol + nt * 16 + m16;  // col = lane&15
                float sc = ISQ * (float)acc[mt][nt][v] + cv[nt];
                if (gj == gi) sc = -INFINITY;
                if (sc > best || (sc == best && gj < bidx)) { best = sc; bidx = gj; }
            }
#pragma unroll
            for (int msk = 1; msk < 16; msk <<= 1) {       // reduce over 16 cols
                float ob = __shfl_xor(best, msk);
                int oi = __shfl_xor(bidx, msk);
                if (ob > best || (ob == best && oi < bidx)) { best = ob; bidx = oi; }
            }
            if (m16 == 0) { rv[wave & 1][lr] = best; ri[wave & 1][lr] = bidx; }
        }
    }
    __syncthreads();
    if (t < BM) {
        float b0 = rv[0][t]; int i0 = ri[0][t];
        float b1 = rv[1][t]; int i1 = ri[1][t];
        if (b1 > b0 || (b1 == b0 && i1 < i0)) { b0 = b1; i0 = i1; }
        const size_t o = (size_t)(rowBase + t) * NCT + blockIdx.x;
        pval[o] = b0;
        pidx[o] = i0;
    }
}

// ---------------------------------------------------------------------------
// K3: reduce 64 partials -> negidx; neg distance exact fp32 from x + stored
// inverse norms; rowloss = relu(pos2 - neg2 + margin). One wave per row.
// (p-row read eliminated: pos2 precomputed in K1.)
// ---------------------------------------------------------------------------
__global__ __launch_bounds__(256) void k_rowloss(
    const float* __restrict__ x,
    const float* __restrict__ rnA, const float* __restrict__ rnP,
    const float* __restrict__ pval, const int* __restrict__ pidx,
    const float* __restrict__ rowpos,
    float* __restrict__ rowloss)
{
    const int wave = threadIdx.x >> 6;
    const int lane = threadIdx.x & 63;
    const int i = blockIdx.x * 4 + wave;

    float best = pval[(size_t)i * NCT + lane];
    int bidx = pidx[(size_t)i * NCT + lane];
#pragma unroll
    for (int msk = 1; msk < 64; msk <<= 1) {
        float ob = __shfl_xor(best, msk);
        int oi = __shfl_xor(bidx, msk);
        if (ob > best || (ob == best && oi < bidx)) { best = ob; bidx = oi; }
    }

    const float ra = rnA[i];
    const float rn = rnP[bidx];
    const float4* av = (const float4*)(x + (size_t)i * (2 * Dn));
    const float4* nv = (const float4*)(x + (size_t)bidx * (2 * Dn) + Dn);
    float ng = 0.f;
#pragma unroll
    for (int c = 0; c < 2; ++c) {
        const int idx = lane + c * 64;
        float4 a4 = av[idx], n4 = nv[idx];
        float u;
        u = a4.x * ra - n4.x * rn + EPSP; ng += u * u;
        u = a4.y * ra - n4.y * rn + EPSP; ng += u * u;
        u = a4.z * ra - n4.z * rn + EPSP; ng += u * u;
        u = a4.w * ra - n4.w * rn + EPSP; ng += u * u;
    }
#pragma unroll
    for (int msk = 1; msk < 64; msk <<= 1) ng += __shfl_xor(ng, msk);

    if (lane == 0) rowloss[i] = fmaxf(rowpos[i] - ng + MARG, 0.f);
}

// ---------------------------------------------------------------------------
// K4: mean over 8192 row losses -> scalar out (deterministic)
// ---------------------------------------------------------------------------
__global__ __launch_bounds__(1024) void k_final(
    const float* __restrict__ rowloss, float* __restrict__ out)
{
    __shared__ float sm[16];
    float s = 0.f;
    for (int k = threadIdx.x; k < Bn; k += 1024) s += rowloss[k];
#pragma unroll
    for (int msk = 1; msk < 64; msk <<= 1) s += __shfl_xor(s, msk);
    if ((threadIdx.x & 63) == 0) sm[threadIdx.x >> 6] = s;
    __syncthreads();
    if (threadIdx.x == 0) {
        float tot = 0.f;
#pragma unroll
        for (int w = 0; w < 16; ++w) tot += sm[w];
        out[0] = tot * (1.0f / Bn);
    }
}

extern "C" void kernel_launch(void* const* d_in, const int* in_sizes, int n_in,
                              void* d_out, int out_size, void* d_ws, size_t ws_size,
                              hipStream_t stream)
{
    const float* x = (const float*)d_in[0];
    char* ws = (char*)d_ws;
    // workspace layout (bytes):
    uint8_t*  a_i8    = (uint8_t*)(ws + 0);          // 4 MB
    uint8_t*  p_i8    = (uint8_t*)(ws + 4194304);    // 4 MB
    float*    rnA     = (float*)(ws + 8388608);      // 32 KB
    float*    rnP     = (float*)(ws + 8421376);      // 32 KB
    float*    cterm   = (float*)(ws + 8454144);      // 32 KB
    float*    pval    = (float*)(ws + 8486912);      // 2 MB
    int*      pidx    = (int*)(ws + 10584064);       // 2 MB
    float*    rowpos  = (float*)(ws + 12681216);     // 32 KB
    float*    rowloss = (float*)(ws + 12713984);     // 32 KB (total ~12.7 MB)
    float*    out     = (float*)d_out;

    k_normalize<<<2048, 256, 0, stream>>>(x, a_i8, p_i8, rnA, rnP, cterm, rowpos);
    k_gemm_argmax<<<dim3(NCT, Bn / BM), 256, 0, stream>>>(a_i8, p_i8, cterm,
                                                          pval, pidx);
    k_rowloss<<<2048, 256, 0, stream>>>(x, rnA, rnP, pval, pidx, rowpos, rowloss);
    k_final<<<1, 1024, 0, stream>>>(rowloss, out);
}

// Round 14
// 150.243 us; speedup vs baseline: 1.9040x; 1.0474x over previous
//
#include <hip/hip_runtime.h>
#include <stdint.h>
#include <math.h>

// Problem constants (B=8192 rows, D=512 features)
#define Bn 8192
#define Dn 512
#define EPSN 1e-12f
#define EPSP 1e-6f
#define MARG 0.3f

// R14 = R13 + (a) transposed partials layout p[ct*Bn+row] (kills the 8x
// partial-line write amplification seen as WRITE_SIZE 33MB vs 4MB logical)
// + (b) packed sortable (score,idx) u64 argmax reduce (halves epilogue VALU).
// GEMM core byte-identical to R11/R13 (i8 16x16x64, 84us @ R11 clocks).
// Ledger: occupancy lever exhausted (R2/R5/R6), B-out-of-LDS loses (R4/R7),
// fp8 spills (R9), i8 2xK wins (R11), single-address atomics +100us (R5),
// ticket+fence +20us (R10), cooperative launch no-ops under capture (R12).
#define BM 128
#define BN 128
#define BKB 64          // k elements (=bytes) per tile
#define KT (Dn / BKB)   // 8 k-iterations
#define NCT (Bn / BN)   // 64 column tiles
#define QS 256.0f
#define ISQ (2.0f / 65536.0f)

typedef int   int4v __attribute__((ext_vector_type(4)));
typedef float f32x4 __attribute__((ext_vector_type(4)));

// async global->LDS, 16B per lane; LDS dest is wave-uniform base + lane*16
__device__ __forceinline__ void async16(const void* g, void* l) {
    __builtin_amdgcn_global_load_lds(
        (const __attribute__((address_space(1))) void*)g,
        (__attribute__((address_space(3))) void*)l,
        16, 0, 0);
}

// pack (score, idx) into one sortable u64: key(f) monotonic, ~idx low so
// max() picks the SMALLEST index on score ties (reference argmax semantics).
__device__ __forceinline__ unsigned long long packSI(float s, int idx) {
    union { float f; unsigned u; } c; c.f = s;
    const unsigned key = (c.u & 0x80000000u) ? ~c.u : (c.u | 0x80000000u);
    return ((unsigned long long)key << 32) | (unsigned)(~idx);
}
__device__ __forceinline__ float unpackS(unsigned long long p) {
    unsigned key = (unsigned)(p >> 32);
    union { unsigned u; float f; } c;
    c.u = (key & 0x80000000u) ? (key ^ 0x80000000u) : ~key;
    return c.f;
}
__device__ __forceinline__ int unpackI(unsigned long long p) {
    return (int)~(unsigned)(p & 0xffffffffu);
}

// ---------------------------------------------------------------------------
// K1: one wave per row pair (a_i, p_i): L2-normalize both -> i8 rows (x256,
// RNE, clamp +-127), inverse norms, column term c[j] = -sp2[j] + 2*eps*sp[j],
// and exact fp32 pos2[i] = sum((a/||a|| - p/||p|| + eps)^2). 2048 blocks.
// Measured at the HBM floor (~80 MB moved, ~12us).
// ---------------------------------------------------------------------------
__global__ __launch_bounds__(256) void k_normalize(
    const float* __restrict__ x,
    uint8_t* __restrict__ a_i8, uint8_t* __restrict__ p_i8,
    float* __restrict__ rnA, float* __restrict__ rnP,
    float* __restrict__ cterm, float* __restrict__ rowpos)
{
    const int wave = threadIdx.x >> 6;
    const int lane = threadIdx.x & 63;
    const int i = blockIdx.x * 4 + wave;   // 0..8191

    const float* srcA = x + (size_t)i * (2 * Dn) + lane * 8;
    const float* srcP = srcA + Dn;
    float4 a0 = ((const float4*)srcA)[0];
    float4 a1 = ((const float4*)srcA)[1];
    float4 p0 = ((const float4*)srcP)[0];
    float4 p1 = ((const float4*)srcP)[1];
    float va[8] = {a0.x, a0.y, a0.z, a0.w, a1.x, a1.y, a1.z, a1.w};
    float vp[8] = {p0.x, p0.y, p0.z, p0.w, p1.x, p1.y, p1.z, p1.w};

    float ssa = 0.f, ssp = 0.f;
#pragma unroll
    for (int j = 0; j < 8; ++j) { ssa += va[j] * va[j]; ssp += vp[j] * vp[j]; }
#pragma unroll
    for (int m = 1; m < 64; m <<= 1) {
        ssa += __shfl_xor(ssa, m);
        ssp += __shfl_xor(ssp, m);
    }
    const float sa = 1.0f / fmaxf(sqrtf(ssa), EPSN);
    const float sp = 1.0f / fmaxf(sqrtf(ssp), EPSN);

    float oa[8], op[8], s1 = 0.f, s2 = 0.f, pos = 0.f;
#pragma unroll
    for (int j = 0; j < 8; ++j) {
        oa[j] = va[j] * sa;
        op[j] = vp[j] * sp;
        s1 += op[j]; s2 += op[j] * op[j];
        const float u = oa[j] - op[j] + EPSP;
        pos += u * u;
    }

    uint64_t pka = 0, pkp = 0;
#pragma unroll
    for (int j = 0; j < 8; ++j) {
        int qa = (int)rintf(oa[j] * QS);
        int qp = (int)rintf(op[j] * QS);
        qa = qa > 127 ? 127 : (qa < -127 ? -127 : qa);
        qp = qp > 127 ? 127 : (qp < -127 ? -127 : qp);
        pka |= (uint64_t)(uint8_t)qa << (8 * j);
        pkp |= (uint64_t)(uint8_t)qp << (8 * j);
    }
    *(uint64_t*)(a_i8 + (size_t)i * Dn + lane * 8) = pka;
    *(uint64_t*)(p_i8 + (size_t)i * Dn + lane * 8) = pkp;

#pragma unroll
    for (int m = 1; m < 64; m <<= 1) {
        s1 += __shfl_xor(s1, m);
        s2 += __shfl_xor(s2, m);
        pos += __shfl_xor(pos, m);
    }
    if (lane == 0) {
        rnA[i] = sa;
        rnP[i] = sp;
        cterm[i] = -s2 + 2.0f * EPSP * s1;
        rowpos[i] = pos;
    }
}

// ---------------------------------------------------------------------------
// K2: i8 MFMA GEMM (a_n @ p_n^T, x65536 scaled, exact int accumulate) +
// fused per-row argmax. K-loop byte-identical to R11/R13. Epilogue: packed
// u64 argmax reduce; partials stored transposed p[ct*Bn+row] (contiguous
// 512 B per block per array -> no write amplification).
// ---------------------------------------------------------------------------
__global__ __launch_bounds__(256, 4) void k_gemm_argmax(
    const uint8_t* __restrict__ a_i8, const uint8_t* __restrict__ p_i8,
    const float* __restrict__ cterm,
    float* __restrict__ pval, int* __restrict__ pidx)
{
    __shared__ uint8_t As[2][BM * BKB];   // 2 x 8 KB
    __shared__ uint8_t Bs[2][BN * BKB];   // 2 x 8 KB
    __shared__ unsigned long long rp[2][BM];   // packed (score,idx)

    const int t = threadIdx.x;
    const int wave = t >> 6;
    const int lane = t & 63;
    const int rowBase = blockIdx.y * BM;
    const int colBase = blockIdx.x * BN;

    const int q = lane >> 4;       // 0..3  (k-chunk)
    const int m16 = lane & 15;     // 0..15
    const int waveRow = (wave >> 1) * 64;
    const int waveCol = (wave & 1) * 64;

    // staging pointers, hoisted (chunk c -> row c>>2, slot c&3 holds global
    // k-chunk (c&3)^((row>>1)&3))
    const int r0 = t >> 2;
    const int g0 = (t & 3) ^ ((r0 >> 1) & 3);
    const int r1 = (256 + t) >> 2;
    const int g1 = ((256 + t) & 3) ^ ((r1 >> 1) & 3);
    const uint8_t* gA0 = a_i8 + (size_t)(rowBase + r0) * Dn + g0 * 16;
    const uint8_t* gA1 = a_i8 + (size_t)(rowBase + r1) * Dn + g1 * 16;
    const uint8_t* gB0 = p_i8 + (size_t)(colBase + r0) * Dn + g0 * 16;
    const uint8_t* gB1 = p_i8 + (size_t)(colBase + r1) * Dn + g1 * 16;
    const int ldsC0 = (wave * 64) * 16;          // bytes; HW adds lane*16
    const int ldsC1 = (256 + wave * 64) * 16;

    // fragment LDS read bases: slot = q ^ ((m16>>1)&3) for ALL mt/nt
    const int s0 = q ^ ((m16 >> 1) & 3);
    const int aBase = (waveRow + m16) * BKB + s0 * 16;   // bytes
    const int bBase = (waveCol + m16) * BKB + s0 * 16;

    int4v acc[4][4];
#pragma unroll
    for (int a = 0; a < 4; ++a)
#pragma unroll
        for (int b = 0; b < 4; ++b) acc[a][b] = (int4v){0, 0, 0, 0};

    auto stage = [&](int buf, int ke) {      // ke = byte offset kt*64
        async16(gA0 + ke, &As[buf][ldsC0]);
        async16(gA1 + ke, &As[buf][ldsC1]);
        async16(gB0 + ke, &Bs[buf][ldsC0]);
        async16(gB1 + ke, &Bs[buf][ldsC1]);
    };

    stage(0, 0);
#pragma unroll
    for (int kt = 0; kt < KT; ++kt) {
        const int cur = kt & 1;
        __syncthreads();                 // tile kt resident; prior buf reads done
        if (kt + 1 < KT) stage(cur ^ 1, (kt + 1) * BKB);  // drains at NEXT barrier

        const uint8_t* pa = &As[cur][aBase];
        const uint8_t* pb = &Bs[cur][bBase];
        int4v af[4], bfr[4];
#pragma unroll
        for (int mt = 0; mt < 4; ++mt)
            af[mt] = *(const int4v*)(pa + mt * 16 * BKB);
#pragma unroll
        for (int nt = 0; nt < 4; ++nt)
            bfr[nt] = *(const int4v*)(pb + nt * 16 * BKB);
#pragma unroll
        for (int mt = 0; mt < 4; ++mt)
#pragma unroll
            for (int nt = 0; nt < 4; ++nt)
                acc[mt][nt] = __builtin_amdgcn_mfma_i32_16x16x64_i8(
                    af[mt], bfr[nt], acc[mt][nt], 0, 0, 0);
    }

    // epilogue: score = 2*idot/65536 + c[j]; mask diagonal; packed argmax
    float cv[4];
#pragma unroll
    for (int nt = 0; nt < 4; ++nt)
        cv[nt] = cterm[colBase + waveCol + nt * 16 + m16];

#pragma unroll
    for (int mt = 0; mt < 4; ++mt) {
#pragma unroll
        for (int v = 0; v < 4; ++v) {
            const int lr = waveRow + mt * 16 + q * 4 + v;   // C/D row = quad*4+reg
            const int gi = rowBase + lr;
            unsigned long long best = 0;   // key 0 = below any real score
#pragma unroll
            for (int nt = 0; nt < 4; ++nt) {
                const int gj = colBase + waveCol + nt * 16 + m16;  // col = lane&15
                float sc = ISQ * (float)acc[mt][nt][v] + cv[nt];
                unsigned long long pk =
                    (gj == gi) ? 0ull : packSI(sc, gj);
                best = pk > best ? pk : best;
            }
#pragma unroll
            for (int msk = 1; msk < 16; msk <<= 1) {       // reduce over 16 cols
                unsigned long long ob = __shfl_xor(best, msk);
                best = ob > best ? ob : best;
            }
            if (m16 == 0) rp[wave & 1][lr] = best;
        }
    }
    __syncthreads();
    if (t < BM) {
        unsigned long long b0 = rp[0][t];
        unsigned long long b1 = rp[1][t];
        if (b1 > b0) b0 = b1;
        // transposed layout: contiguous 512 B per block per array
        const size_t o = (size_t)blockIdx.x * Bn + rowBase + t;
        pval[o] = unpackS(b0);
        pidx[o] = unpackI(b0);
    }
}

// ---------------------------------------------------------------------------
// K3: reduce 64 partials (transposed layout: lane ct reads p[ct*Bn+i]) ->
// negidx; neg distance exact fp32; rowloss = relu(pos2 - neg2 + margin).
// One wave per row; partial arrays are 8 MB, L2/L3-resident.
// ---------------------------------------------------------------------------
__global__ __launch_bounds__(256) void k_rowloss(
    const float* __restrict__ x,
    const float* __restrict__ rnA, const float* __restrict__ rnP,
    const float* __restrict__ pval, const int* __restrict__ pidx,
    const float* __restrict__ rowpos,
    float* __restrict__ rowloss)
{
    const int wave = threadIdx.x >> 6;
    const int lane = threadIdx.x & 63;
    const int i = blockIdx.x * 4 + wave;

    float best = pval[(size_t)lane * Bn + i];
    int bidx = pidx[(size_t)lane * Bn + i];
#pragma unroll
    for (int msk = 1; msk < 64; msk <<= 1) {
        float ob = __shfl_xor(best, msk);
        int oi = __shfl_xor(bidx, msk);
        if (ob > best || (ob == best && oi < bidx)) { best = ob; bidx = oi; }
    }

    const float ra = rnA[i];
    const float rn = rnP[bidx];
    const float4* av = (const float4*)(x + (size_t)i * (2 * Dn));
    const float4* nv = (const float4*)(x + (size_t)bidx * (2 * Dn) + Dn);
    float ng = 0.f;
#pragma unroll
    for (int c = 0; c < 2; ++c) {
        const int idx = lane + c * 64;
        float4 a4 = av[idx], n4 = nv[idx];
        float u;
        u = a4.x * ra - n4.x * rn + EPSP; ng += u * u;
        u = a4.y * ra - n4.y * rn + EPSP; ng += u * u;
        u = a4.z * ra - n4.z * rn + EPSP; ng += u * u;
        u = a4.w * ra - n4.w * rn + EPSP; ng += u * u;
    }
#pragma unroll
    for (int msk = 1; msk < 64; msk <<= 1) ng += __shfl_xor(ng, msk);

    if (lane == 0) rowloss[i] = fmaxf(rowpos[i] - ng + MARG, 0.f);
}

// ---------------------------------------------------------------------------
// K4: mean over 8192 row losses -> scalar out (deterministic)
// ---------------------------------------------------------------------------
__global__ __launch_bounds__(1024) void k_final(
    const float* __restrict__ rowloss, float* __restrict__ out)
{
    __shared__ float sm[16];
    float s = 0.f;
    for (int k = threadIdx.x; k < Bn; k += 1024) s += rowloss[k];
#pragma unroll
    for (int msk = 1; msk < 64; msk <<= 1) s += __shfl_xor(s, msk);
    if ((threadIdx.x & 63) == 0) sm[threadIdx.x >> 6] = s;
    __syncthreads();
    if (threadIdx.x == 0) {
        float tot = 0.f;
#pragma unroll
        for (int w = 0; w < 16; ++w) tot += sm[w];
        out[0] = tot * (1.0f / Bn);
    }
}

extern "C" void kernel_launch(void* const* d_in, const int* in_sizes, int n_in,
                              void* d_out, int out_size, void* d_ws, size_t ws_size,
                              hipStream_t stream)
{
    const float* x = (const float*)d_in[0];
    char* ws = (char*)d_ws;
    // workspace layout (bytes):
    uint8_t*  a_i8    = (uint8_t*)(ws + 0);          // 4 MB
    uint8_t*  p_i8    = (uint8_t*)(ws + 4194304);    // 4 MB
    float*    rnA     = (float*)(ws + 8388608);      // 32 KB
    float*    rnP     = (float*)(ws + 8421376);      // 32 KB
    float*    cterm   = (float*)(ws + 8454144);      // 32 KB
    float*    pval    = (float*)(ws + 8486912);      // 2 MB (transposed)
    int*      pidx    = (int*)(ws + 10584064);       // 2 MB (transposed)
    float*    rowpos  = (float*)(ws + 12681216);     // 32 KB
    float*    rowloss = (float*)(ws + 12713984);     // 32 KB (total ~12.7 MB)
    float*    out     = (float*)d_out;

    k_normalize<<<2048, 256, 0, stream>>>(x, a_i8, p_i8, rnA, rnP, cterm, rowpos);
    k_gemm_argmax<<<dim3(NCT, Bn / BM), 256, 0, stream>>>(a_i8, p_i8, cterm,
                                                          pval, pidx);
    k_rowloss<<<2048, 256, 0, stream>>>(x, rnA, rnP, pval, pidx, rowpos, rowloss);
    k_final<<<1, 1024, 0, stream>>>(rowloss, out);
}

// Round 15
// 143.386 us; speedup vs baseline: 1.9951x; 1.0478x over previous
//
#include <hip/hip_runtime.h>
#include <stdint.h>
#include <math.h>

// Problem constants (B=8192 rows, D=512 features)
#define Bn 8192
#define Dn 512
#define EPSN 1e-12f
#define EPSP 1e-6f
#define MARG 0.3f

// R15 = R14 + packed (score,idx) u64 carried end-to-end (K2 stores the
// packed value directly; K3 does a branch-free u64-max reduce).
// GEMM core byte-identical to R11/R13/R14 (i8 16x16x64; R14: 68us,
// MfmaUtil 20.5, WRITE 4.1MB, 0 conflicts, absmax 0.0).
// Session ledger: occupancy lever exhausted (R2/R5/R6), B-out-of-LDS loses
// (R4/R7), fp8 mfma_scale spills (R9), i8 2xK wins (R11), transposed
// partials kill 8x write amplification (R14), single-address atomics +100us
// (R5), ticket+fence +20us (R10), cooperative launch no-ops under graph
// capture (R12).
#define BM 128
#define BN 128
#define BKB 64          // k elements (=bytes) per tile
#define KT (Dn / BKB)   // 8 k-iterations
#define NCT (Bn / BN)   // 64 column tiles
#define QS 256.0f
#define ISQ (2.0f / 65536.0f)

typedef int   int4v __attribute__((ext_vector_type(4)));
typedef float f32x4 __attribute__((ext_vector_type(4)));

// async global->LDS, 16B per lane; LDS dest is wave-uniform base + lane*16
__device__ __forceinline__ void async16(const void* g, void* l) {
    __builtin_amdgcn_global_load_lds(
        (const __attribute__((address_space(1))) void*)g,
        (__attribute__((address_space(3))) void*)l,
        16, 0, 0);
}

// pack (score, idx) into one sortable u64: key(f) monotonic in f, ~idx low
// so max() picks the SMALLEST index on score ties (reference semantics).
__device__ __forceinline__ unsigned long long packSI(float s, int idx) {
    union { float f; unsigned u; } c; c.f = s;
    const unsigned key = (c.u & 0x80000000u) ? ~c.u : (c.u | 0x80000000u);
    return ((unsigned long long)key << 32) | (unsigned)(~idx);
}
__device__ __forceinline__ int unpackI(unsigned long long p) {
    return (int)~(unsigned)(p & 0xffffffffu);
}

// ---------------------------------------------------------------------------
// K1: one wave per row pair (a_i, p_i): L2-normalize both -> i8 rows (x256,
// RNE, clamp +-127), inverse norms, column term c[j] = -sp2[j] + 2*eps*sp[j],
// and exact fp32 pos2[i]. 2048 blocks. Measured at the HBM floor.
// ---------------------------------------------------------------------------
__global__ __launch_bounds__(256) void k_normalize(
    const float* __restrict__ x,
    uint8_t* __restrict__ a_i8, uint8_t* __restrict__ p_i8,
    float* __restrict__ rnA, float* __restrict__ rnP,
    float* __restrict__ cterm, float* __restrict__ rowpos)
{
    const int wave = threadIdx.x >> 6;
    const int lane = threadIdx.x & 63;
    const int i = blockIdx.x * 4 + wave;   // 0..8191

    const float* srcA = x + (size_t)i * (2 * Dn) + lane * 8;
    const float* srcP = srcA + Dn;
    float4 a0 = ((const float4*)srcA)[0];
    float4 a1 = ((const float4*)srcA)[1];
    float4 p0 = ((const float4*)srcP)[0];
    float4 p1 = ((const float4*)srcP)[1];
    float va[8] = {a0.x, a0.y, a0.z, a0.w, a1.x, a1.y, a1.z, a1.w};
    float vp[8] = {p0.x, p0.y, p0.z, p0.w, p1.x, p1.y, p1.z, p1.w};

    float ssa = 0.f, ssp = 0.f;
#pragma unroll
    for (int j = 0; j < 8; ++j) { ssa += va[j] * va[j]; ssp += vp[j] * vp[j]; }
#pragma unroll
    for (int m = 1; m < 64; m <<= 1) {
        ssa += __shfl_xor(ssa, m);
        ssp += __shfl_xor(ssp, m);
    }
    const float sa = 1.0f / fmaxf(sqrtf(ssa), EPSN);
    const float sp = 1.0f / fmaxf(sqrtf(ssp), EPSN);

    float oa[8], op[8], s1 = 0.f, s2 = 0.f, pos = 0.f;
#pragma unroll
    for (int j = 0; j < 8; ++j) {
        oa[j] = va[j] * sa;
        op[j] = vp[j] * sp;
        s1 += op[j]; s2 += op[j] * op[j];
        const float u = oa[j] - op[j] + EPSP;
        pos += u * u;
    }

    uint64_t pka = 0, pkp = 0;
#pragma unroll
    for (int j = 0; j < 8; ++j) {
        int qa = (int)rintf(oa[j] * QS);
        int qp = (int)rintf(op[j] * QS);
        qa = qa > 127 ? 127 : (qa < -127 ? -127 : qa);
        qp = qp > 127 ? 127 : (qp < -127 ? -127 : qp);
        pka |= (uint64_t)(uint8_t)qa << (8 * j);
        pkp |= (uint64_t)(uint8_t)qp << (8 * j);
    }
    *(uint64_t*)(a_i8 + (size_t)i * Dn + lane * 8) = pka;
    *(uint64_t*)(p_i8 + (size_t)i * Dn + lane * 8) = pkp;

#pragma unroll
    for (int m = 1; m < 64; m <<= 1) {
        s1 += __shfl_xor(s1, m);
        s2 += __shfl_xor(s2, m);
        pos += __shfl_xor(pos, m);
    }
    if (lane == 0) {
        rnA[i] = sa;
        rnP[i] = sp;
        cterm[i] = -s2 + 2.0f * EPSP * s1;
        rowpos[i] = pos;
    }
}

// ---------------------------------------------------------------------------
// K2: i8 MFMA GEMM (a_n @ p_n^T, x65536 scaled, exact int accumulate) +
// fused per-row argmax. K-loop byte-identical to R11/R13/R14. Epilogue:
// packed u64 argmax; partials stored packed+transposed ppack[ct*Bn+row]
// (1 KB contiguous per block -> no write amplification).
// ---------------------------------------------------------------------------
__global__ __launch_bounds__(256, 4) void k_gemm_argmax(
    const uint8_t* __restrict__ a_i8, const uint8_t* __restrict__ p_i8,
    const float* __restrict__ cterm,
    unsigned long long* __restrict__ ppack)
{
    __shared__ uint8_t As[2][BM * BKB];   // 2 x 8 KB
    __shared__ uint8_t Bs[2][BN * BKB];   // 2 x 8 KB
    __shared__ unsigned long long rp[2][BM];   // packed (score,idx)

    const int t = threadIdx.x;
    const int wave = t >> 6;
    const int lane = t & 63;
    const int rowBase = blockIdx.y * BM;
    const int colBase = blockIdx.x * BN;

    const int q = lane >> 4;       // 0..3  (k-chunk)
    const int m16 = lane & 15;     // 0..15
    const int waveRow = (wave >> 1) * 64;
    const int waveCol = (wave & 1) * 64;

    // staging pointers, hoisted (chunk c -> row c>>2, slot c&3 holds global
    // k-chunk (c&3)^((row>>1)&3))
    const int r0 = t >> 2;
    const int g0 = (t & 3) ^ ((r0 >> 1) & 3);
    const int r1 = (256 + t) >> 2;
    const int g1 = ((256 + t) & 3) ^ ((r1 >> 1) & 3);
    const uint8_t* gA0 = a_i8 + (size_t)(rowBase + r0) * Dn + g0 * 16;
    const uint8_t* gA1 = a_i8 + (size_t)(rowBase + r1) * Dn + g1 * 16;
    const uint8_t* gB0 = p_i8 + (size_t)(colBase + r0) * Dn + g0 * 16;
    const uint8_t* gB1 = p_i8 + (size_t)(colBase + r1) * Dn + g1 * 16;
    const int ldsC0 = (wave * 64) * 16;          // bytes; HW adds lane*16
    const int ldsC1 = (256 + wave * 64) * 16;

    // fragment LDS read bases: slot = q ^ ((m16>>1)&3) for ALL mt/nt
    const int s0 = q ^ ((m16 >> 1) & 3);
    const int aBase = (waveRow + m16) * BKB + s0 * 16;   // bytes
    const int bBase = (waveCol + m16) * BKB + s0 * 16;

    int4v acc[4][4];
#pragma unroll
    for (int a = 0; a < 4; ++a)
#pragma unroll
        for (int b = 0; b < 4; ++b) acc[a][b] = (int4v){0, 0, 0, 0};

    auto stage = [&](int buf, int ke) {      // ke = byte offset kt*64
        async16(gA0 + ke, &As[buf][ldsC0]);
        async16(gA1 + ke, &As[buf][ldsC1]);
        async16(gB0 + ke, &Bs[buf][ldsC0]);
        async16(gB1 + ke, &Bs[buf][ldsC1]);
    };

    stage(0, 0);
#pragma unroll
    for (int kt = 0; kt < KT; ++kt) {
        const int cur = kt & 1;
        __syncthreads();                 // tile kt resident; prior buf reads done
        if (kt + 1 < KT) stage(cur ^ 1, (kt + 1) * BKB);  // drains at NEXT barrier

        const uint8_t* pa = &As[cur][aBase];
        const uint8_t* pb = &Bs[cur][bBase];
        int4v af[4], bfr[4];
#pragma unroll
        for (int mt = 0; mt < 4; ++mt)
            af[mt] = *(const int4v*)(pa + mt * 16 * BKB);
#pragma unroll
        for (int nt = 0; nt < 4; ++nt)
            bfr[nt] = *(const int4v*)(pb + nt * 16 * BKB);
#pragma unroll
        for (int mt = 0; mt < 4; ++mt)
#pragma unroll
            for (int nt = 0; nt < 4; ++nt)
                acc[mt][nt] = __builtin_amdgcn_mfma_i32_16x16x64_i8(
                    af[mt], bfr[nt], acc[mt][nt], 0, 0, 0);
    }

    // epilogue: score = 2*idot/65536 + c[j]; mask diagonal; packed argmax
    float cv[4];
#pragma unroll
    for (int nt = 0; nt < 4; ++nt)
        cv[nt] = cterm[colBase + waveCol + nt * 16 + m16];

#pragma unroll
    for (int mt = 0; mt < 4; ++mt) {
#pragma unroll
        for (int v = 0; v < 4; ++v) {
            const int lr = waveRow + mt * 16 + q * 4 + v;   // C/D row = quad*4+reg
            const int gi = rowBase + lr;
            unsigned long long best = 0;   // key 0 = below any real score
#pragma unroll
            for (int nt = 0; nt < 4; ++nt) {
                const int gj = colBase + waveCol + nt * 16 + m16;  // col = lane&15
                float sc = ISQ * (float)acc[mt][nt][v] + cv[nt];
                unsigned long long pk = (gj == gi) ? 0ull : packSI(sc, gj);
                best = pk > best ? pk : best;
            }
#pragma unroll
            for (int msk = 1; msk < 16; msk <<= 1) {       // reduce over 16 cols
                unsigned long long ob = __shfl_xor(best, msk);
                best = ob > best ? ob : best;
            }
            if (m16 == 0) rp[wave & 1][lr] = best;
        }
    }
    __syncthreads();
    if (t < BM) {
        unsigned long long b0 = rp[0][t];
        unsigned long long b1 = rp[1][t];
        if (b1 > b0) b0 = b1;
        // packed + transposed: 1 KB contiguous per block
        ppack[(size_t)blockIdx.x * Bn + rowBase + t] = b0;
    }
}

// ---------------------------------------------------------------------------
// K3: branch-free u64-max over 64 packed partials -> negidx; neg distance in
// exact fp32 from x + stored inverse norms; rowloss = relu(pos2-neg2+margin).
// One wave per row.
// ---------------------------------------------------------------------------
__global__ __launch_bounds__(256) void k_rowloss(
    const float* __restrict__ x,
    const float* __restrict__ rnA, const float* __restrict__ rnP,
    const unsigned long long* __restrict__ ppack,
    const float* __restrict__ rowpos,
    float* __restrict__ rowloss)
{
    const int wave = threadIdx.x >> 6;
    const int lane = threadIdx.x & 63;
    const int i = blockIdx.x * 4 + wave;

    unsigned long long best = ppack[(size_t)lane * Bn + i];
#pragma unroll
    for (int msk = 1; msk < 64; msk <<= 1) {
        unsigned long long ob = __shfl_xor(best, msk);
        best = ob > best ? ob : best;
    }
    const int bidx = unpackI(best);

    const float ra = rnA[i];
    const float rn = rnP[bidx];
    const float4* av = (const float4*)(x + (size_t)i * (2 * Dn));
    const float4* nv = (const float4*)(x + (size_t)bidx * (2 * Dn) + Dn);
    float ng = 0.f;
#pragma unroll
    for (int c = 0; c < 2; ++c) {
        const int idx = lane + c * 64;
        float4 a4 = av[idx], n4 = nv[idx];
        float u;
        u = a4.x * ra - n4.x * rn + EPSP; ng += u * u;
        u = a4.y * ra - n4.y * rn + EPSP; ng += u * u;
        u = a4.z * ra - n4.z * rn + EPSP; ng += u * u;
        u = a4.w * ra - n4.w * rn + EPSP; ng += u * u;
    }
#pragma unroll
    for (int msk = 1; msk < 64; msk <<= 1) ng += __shfl_xor(ng, msk);

    if (lane == 0) rowloss[i] = fmaxf(rowpos[i] - ng + MARG, 0.f);
}

// ---------------------------------------------------------------------------
// K4: mean over 8192 row losses -> scalar out (deterministic)
// ---------------------------------------------------------------------------
__global__ __launch_bounds__(1024) void k_final(
    const float* __restrict__ rowloss, float* __restrict__ out)
{
    __shared__ float sm[16];
    float s = 0.f;
    for (int k = threadIdx.x; k < Bn; k += 1024) s += rowloss[k];
#pragma unroll
    for (int msk = 1; msk < 64; msk <<= 1) s += __shfl_xor(s, msk);
    if ((threadIdx.x & 63) == 0) sm[threadIdx.x >> 6] = s;
    __syncthreads();
    if (threadIdx.x == 0) {
        float tot = 0.f;
#pragma unroll
        for (int w = 0; w < 16; ++w) tot += sm[w];
        out[0] = tot * (1.0f / Bn);
    }
}

extern "C" void kernel_launch(void* const* d_in, const int* in_sizes, int n_in,
                              void* d_out, int out_size, void* d_ws, size_t ws_size,
                              hipStream_t stream)
{
    const float* x = (const float*)d_in[0];
    char* ws = (char*)d_ws;
    // workspace layout (bytes):
    uint8_t*  a_i8    = (uint8_t*)(ws + 0);          // 4 MB
    uint8_t*  p_i8    = (uint8_t*)(ws + 4194304);    // 4 MB
    float*    rnA     = (float*)(ws + 8388608);      // 32 KB
    float*    rnP     = (float*)(ws + 8421376);      // 32 KB
    float*    cterm   = (float*)(ws + 8454144);      // 32 KB
    unsigned long long* ppack =
        (unsigned long long*)(ws + 8486912);         // 4 MB (packed, transposed)
    float*    rowpos  = (float*)(ws + 12681216);     // 32 KB
    float*    rowloss = (float*)(ws + 12713984);     // 32 KB (total ~12.7 MB)
    float*    out     = (float*)d_out;

    k_normalize<<<2048, 256, 0, stream>>>(x, a_i8, p_i8, rnA, rnP, cterm, rowpos);
    k_gemm_argmax<<<dim3(NCT, Bn / BM), 256, 0, stream>>>(a_i8, p_i8, cterm, ppack);
    k_rowloss<<<2048, 256, 0, stream>>>(x, rnA, rnP, ppack, rowpos, rowloss);
    k_final<<<1, 1024, 0, stream>>>(rowloss, out);
}

// Round 16
// 138.500 us; speedup vs baseline: 2.0654x; 1.0353x over previous
//
#include <hip/hip_runtime.h>
#include <stdint.h>
#include <math.h>

// Problem constants (B=8192 rows, D=512 features)
#define Bn 8192
#define Dn 512
#define EPSN 1e-12f
#define EPSP 1e-6f
#define MARG 0.3f

// R16 = R15 + algebraic tail: neg^2 = (sa2 + 2*eps*sa + D*eps^2) - score, so
// loss_i = relu(rowconst[i] + score_max[i]) with rowconst computed exactly in
// K1. K3 loses its random x-gather entirely (was its whole cost) and emits
// per-block partial sums; K4 sums 2048 partials. GEMM core byte-identical to
// R11/R13/R14/R15 (i8 16x16x64; 68-70us, MfmaUtil 20, WRITE 4MB, 0 conflicts).
// Session ledger: occupancy lever exhausted (R2/R5/R6), B-out-of-LDS loses
// (R4/R7), fp8 mfma_scale spills (R9), i8 2xK wins (R11), transposed packed
// partials kill write amplification (R14/R15), single-address atomics +100us
// (R5), ticket+fence +20us (R10), cooperative launch no-ops under capture (R12).
#define BM 128
#define BN 128
#define BKB 64          // k elements (=bytes) per tile
#define KT (Dn / BKB)   // 8 k-iterations
#define NCT (Bn / BN)   // 64 column tiles
#define QS 256.0f
#define ISQ (2.0f / 65536.0f)

typedef int   int4v __attribute__((ext_vector_type(4)));
typedef float f32x4 __attribute__((ext_vector_type(4)));

// async global->LDS, 16B per lane; LDS dest is wave-uniform base + lane*16
__device__ __forceinline__ void async16(const void* g, void* l) {
    __builtin_amdgcn_global_load_lds(
        (const __attribute__((address_space(1))) void*)g,
        (__attribute__((address_space(3))) void*)l,
        16, 0, 0);
}

// pack (score, idx) into one sortable u64: key(f) monotonic in f, ~idx low
// so max() picks the SMALLEST index on score ties (reference semantics).
__device__ __forceinline__ unsigned long long packSI(float s, int idx) {
    union { float f; unsigned u; } c; c.f = s;
    const unsigned key = (c.u & 0x80000000u) ? ~c.u : (c.u | 0x80000000u);
    return ((unsigned long long)key << 32) | (unsigned)(~idx);
}
__device__ __forceinline__ float unpackS(unsigned long long p) {
    unsigned key = (unsigned)(p >> 32);
    union { unsigned u; float f; } c;
    c.u = (key & 0x80000000u) ? (key ^ 0x80000000u) : ~key;
    return c.f;
}

// ---------------------------------------------------------------------------
// K1: one wave per row pair (a_i, p_i): L2-normalize both -> i8 rows (x256,
// RNE, clamp +-127), column term c[j] = -sp2[j] + 2*eps*sp[j], and
// rowconst[i] = pos2[i] - sa2[i] - 2*eps*sa[i] - D*eps^2 + MARGIN (all sums
// exact fp32 over the normalized values). 2048 blocks; at the HBM floor.
// ---------------------------------------------------------------------------
__global__ __launch_bounds__(256) void k_normalize(
    const float* __restrict__ x,
    uint8_t* __restrict__ a_i8, uint8_t* __restrict__ p_i8,
    float* __restrict__ cterm, float* __restrict__ rowconst)
{
    const int wave = threadIdx.x >> 6;
    const int lane = threadIdx.x & 63;
    const int i = blockIdx.x * 4 + wave;   // 0..8191

    const float* srcA = x + (size_t)i * (2 * Dn) + lane * 8;
    const float* srcP = srcA + Dn;
    float4 a0 = ((const float4*)srcA)[0];
    float4 a1 = ((const float4*)srcA)[1];
    float4 p0 = ((const float4*)srcP)[0];
    float4 p1 = ((const float4*)srcP)[1];
    float va[8] = {a0.x, a0.y, a0.z, a0.w, a1.x, a1.y, a1.z, a1.w};
    float vp[8] = {p0.x, p0.y, p0.z, p0.w, p1.x, p1.y, p1.z, p1.w};

    float ssa = 0.f, ssp = 0.f;
#pragma unroll
    for (int j = 0; j < 8; ++j) { ssa += va[j] * va[j]; ssp += vp[j] * vp[j]; }
#pragma unroll
    for (int m = 1; m < 64; m <<= 1) {
        ssa += __shfl_xor(ssa, m);
        ssp += __shfl_xor(ssp, m);
    }
    const float sa = 1.0f / fmaxf(sqrtf(ssa), EPSN);
    const float sp = 1.0f / fmaxf(sqrtf(ssp), EPSN);

    float oa[8], op[8];
    float s1p = 0.f, s2p = 0.f, s1a = 0.f, s2a = 0.f, pos = 0.f;
#pragma unroll
    for (int j = 0; j < 8; ++j) {
        oa[j] = va[j] * sa;
        op[j] = vp[j] * sp;
        s1p += op[j]; s2p += op[j] * op[j];
        s1a += oa[j]; s2a += oa[j] * oa[j];
        const float u = oa[j] - op[j] + EPSP;
        pos += u * u;
    }

    uint64_t pka = 0, pkp = 0;
#pragma unroll
    for (int j = 0; j < 8; ++j) {
        int qa = (int)rintf(oa[j] * QS);
        int qp = (int)rintf(op[j] * QS);
        qa = qa > 127 ? 127 : (qa < -127 ? -127 : qa);
        qp = qp > 127 ? 127 : (qp < -127 ? -127 : qp);
        pka |= (uint64_t)(uint8_t)qa << (8 * j);
        pkp |= (uint64_t)(uint8_t)qp << (8 * j);
    }
    *(uint64_t*)(a_i8 + (size_t)i * Dn + lane * 8) = pka;
    *(uint64_t*)(p_i8 + (size_t)i * Dn + lane * 8) = pkp;

#pragma unroll
    for (int m = 1; m < 64; m <<= 1) {
        s1p += __shfl_xor(s1p, m);
        s2p += __shfl_xor(s2p, m);
        s1a += __shfl_xor(s1a, m);
        s2a += __shfl_xor(s2a, m);
        pos += __shfl_xor(pos, m);
    }
    if (lane == 0) {
        cterm[i] = -s2p + 2.0f * EPSP * s1p;
        rowconst[i] = pos - s2a - 2.0f * EPSP * s1a
                      - (float)Dn * EPSP * EPSP + MARG;
    }
}

// ---------------------------------------------------------------------------
// K2: i8 MFMA GEMM (a_n @ p_n^T, x65536 scaled, exact int accumulate) +
// fused per-row argmax. K-loop byte-identical to R11/R13/R14/R15. Epilogue:
// packed u64 argmax; partials stored packed+transposed ppack[ct*Bn+row].
// ---------------------------------------------------------------------------
__global__ __launch_bounds__(256, 4) void k_gemm_argmax(
    const uint8_t* __restrict__ a_i8, const uint8_t* __restrict__ p_i8,
    const float* __restrict__ cterm,
    unsigned long long* __restrict__ ppack)
{
    __shared__ uint8_t As[2][BM * BKB];   // 2 x 8 KB
    __shared__ uint8_t Bs[2][BN * BKB];   // 2 x 8 KB
    __shared__ unsigned long long rp[2][BM];   // packed (score,idx)

    const int t = threadIdx.x;
    const int wave = t >> 6;
    const int lane = t & 63;
    const int rowBase = blockIdx.y * BM;
    const int colBase = blockIdx.x * BN;

    const int q = lane >> 4;       // 0..3  (k-chunk)
    const int m16 = lane & 15;     // 0..15
    const int waveRow = (wave >> 1) * 64;
    const int waveCol = (wave & 1) * 64;

    // staging pointers, hoisted (chunk c -> row c>>2, slot c&3 holds global
    // k-chunk (c&3)^((row>>1)&3))
    const int r0 = t >> 2;
    const int g0 = (t & 3) ^ ((r0 >> 1) & 3);
    const int r1 = (256 + t) >> 2;
    const int g1 = ((256 + t) & 3) ^ ((r1 >> 1) & 3);
    const uint8_t* gA0 = a_i8 + (size_t)(rowBase + r0) * Dn + g0 * 16;
    const uint8_t* gA1 = a_i8 + (size_t)(rowBase + r1) * Dn + g1 * 16;
    const uint8_t* gB0 = p_i8 + (size_t)(colBase + r0) * Dn + g0 * 16;
    const uint8_t* gB1 = p_i8 + (size_t)(colBase + r1) * Dn + g1 * 16;
    const int ldsC0 = (wave * 64) * 16;          // bytes; HW adds lane*16
    const int ldsC1 = (256 + wave * 64) * 16;

    // fragment LDS read bases: slot = q ^ ((m16>>1)&3) for ALL mt/nt
    const int s0 = q ^ ((m16 >> 1) & 3);
    const int aBase = (waveRow + m16) * BKB + s0 * 16;   // bytes
    const int bBase = (waveCol + m16) * BKB + s0 * 16;

    int4v acc[4][4];
#pragma unroll
    for (int a = 0; a < 4; ++a)
#pragma unroll
        for (int b = 0; b < 4; ++b) acc[a][b] = (int4v){0, 0, 0, 0};

    auto stage = [&](int buf, int ke) {      // ke = byte offset kt*64
        async16(gA0 + ke, &As[buf][ldsC0]);
        async16(gA1 + ke, &As[buf][ldsC1]);
        async16(gB0 + ke, &Bs[buf][ldsC0]);
        async16(gB1 + ke, &Bs[buf][ldsC1]);
    };

    stage(0, 0);
#pragma unroll
    for (int kt = 0; kt < KT; ++kt) {
        const int cur = kt & 1;
        __syncthreads();                 // tile kt resident; prior buf reads done
        if (kt + 1 < KT) stage(cur ^ 1, (kt + 1) * BKB);  // drains at NEXT barrier

        const uint8_t* pa = &As[cur][aBase];
        const uint8_t* pb = &Bs[cur][bBase];
        int4v af[4], bfr[4];
#pragma unroll
        for (int mt = 0; mt < 4; ++mt)
            af[mt] = *(const int4v*)(pa + mt * 16 * BKB);
#pragma unroll
        for (int nt = 0; nt < 4; ++nt)
            bfr[nt] = *(const int4v*)(pb + nt * 16 * BKB);
#pragma unroll
        for (int mt = 0; mt < 4; ++mt)
#pragma unroll
            for (int nt = 0; nt < 4; ++nt)
                acc[mt][nt] = __builtin_amdgcn_mfma_i32_16x16x64_i8(
                    af[mt], bfr[nt], acc[mt][nt], 0, 0, 0);
    }

    // epilogue: score = 2*idot/65536 + c[j]; mask diagonal; packed argmax
    float cv[4];
#pragma unroll
    for (int nt = 0; nt < 4; ++nt)
        cv[nt] = cterm[colBase + waveCol + nt * 16 + m16];

#pragma unroll
    for (int mt = 0; mt < 4; ++mt) {
#pragma unroll
        for (int v = 0; v < 4; ++v) {
            const int lr = waveRow + mt * 16 + q * 4 + v;   // C/D row = quad*4+reg
            const int gi = rowBase + lr;
            unsigned long long best = 0;   // key 0 = below any real score
#pragma unroll
            for (int nt = 0; nt < 4; ++nt) {
                const int gj = colBase + waveCol + nt * 16 + m16;  // col = lane&15
                float sc = ISQ * (float)acc[mt][nt][v] + cv[nt];
                unsigned long long pk = (gj == gi) ? 0ull : packSI(sc, gj);
                best = pk > best ? pk : best;
            }
#pragma unroll
            for (int msk = 1; msk < 16; msk <<= 1) {       // reduce over 16 cols
                unsigned long long ob = __shfl_xor(best, msk);
                best = ob > best ? ob : best;
            }
            if (m16 == 0) rp[wave & 1][lr] = best;
        }
    }
    __syncthreads();
    if (t < BM) {
        unsigned long long b0 = rp[0][t];
        unsigned long long b1 = rp[1][t];
        if (b1 > b0) b0 = b1;
        // packed + transposed: 1 KB contiguous per block
        ppack[(size_t)blockIdx.x * Bn + rowBase + t] = b0;
    }
}

// ---------------------------------------------------------------------------
// K3: per row - branch-free u64-max over 64 packed partials -> best score;
// loss_i = relu(rowconst[i] + score). No x gather. Per-block partial sum
// (4 rows/block, fixed order) -> partial[]. One wave per row.
// ---------------------------------------------------------------------------
__global__ __launch_bounds__(256) void k_rowloss(
    const unsigned long long* __restrict__ ppack,
    const float* __restrict__ rowconst,
    float* __restrict__ partial)
{
    __shared__ float sm[4];
    const int wave = threadIdx.x >> 6;
    const int lane = threadIdx.x & 63;
    const int i = blockIdx.x * 4 + wave;

    unsigned long long best = ppack[(size_t)lane * Bn + i];
#pragma unroll
    for (int msk = 1; msk < 64; msk <<= 1) {
        unsigned long long ob = __shfl_xor(best, msk);
        best = ob > best ? ob : best;
    }

    if (lane == 0)
        sm[wave] = fmaxf(rowconst[i] + unpackS(best), 0.f);
    __syncthreads();
    if (threadIdx.x == 0)
        partial[blockIdx.x] = (sm[0] + sm[1] + sm[2] + sm[3]) * (1.0f / Bn);
}

// ---------------------------------------------------------------------------
// K4: sum 2048 partials -> scalar out (deterministic)
// ---------------------------------------------------------------------------
__global__ __launch_bounds__(1024) void k_final(
    const float* __restrict__ partial, float* __restrict__ out)
{
    __shared__ float sm[16];
    float s = 0.f;
    for (int k = threadIdx.x; k < 2048; k += 1024) s += partial[k];
#pragma unroll
    for (int msk = 1; msk < 64; msk <<= 1) s += __shfl_xor(s, msk);
    if ((threadIdx.x & 63) == 0) sm[threadIdx.x >> 6] = s;
    __syncthreads();
    if (threadIdx.x == 0) {
        float tot = 0.f;
#pragma unroll
        for (int w = 0; w < 16; ++w) tot += sm[w];
        out[0] = tot;
    }
}

extern "C" void kernel_launch(void* const* d_in, const int* in_sizes, int n_in,
                              void* d_out, int out_size, void* d_ws, size_t ws_size,
                              hipStream_t stream)
{
    const float* x = (const float*)d_in[0];
    char* ws = (char*)d_ws;
    // workspace layout (bytes):
    uint8_t*  a_i8     = (uint8_t*)(ws + 0);         // 4 MB
    uint8_t*  p_i8     = (uint8_t*)(ws + 4194304);   // 4 MB
    float*    cterm    = (float*)(ws + 8388608);     // 32 KB
    float*    rowconst = (float*)(ws + 8421376);     // 32 KB
    unsigned long long* ppack =
        (unsigned long long*)(ws + 8454144);         // 4 MB (packed, transposed)
    float*    partial  = (float*)(ws + 12648448);    // 8 KB (total ~12.7 MB)
    float*    out      = (float*)d_out;

    k_normalize<<<2048, 256, 0, stream>>>(x, a_i8, p_i8, cterm, rowconst);
    k_gemm_argmax<<<dim3(NCT, Bn / BM), 256, 0, stream>>>(a_i8, p_i8, cterm, ppack);
    k_rowloss<<<2048, 256, 0, stream>>>(ppack, rowconst, partial);
    k_final<<<1, 1024, 0, stream>>>(partial, out);
}

// Round 17
// 137.862 us; speedup vs baseline: 2.0750x; 1.0046x over previous
//
#include <hip/hip_runtime.h>
#include <stdint.h>
#include <math.h>

// Problem constants (B=8192 rows, D=512 features)
#define Bn 8192
#define Dn 512
#define EPSN 1e-12f
#define EPSP 1e-6f
#define MARG 0.3f

// R17 = R16 with the partials pass removed: K2's per-(rowtile,coltile) packed
// maxima go straight into rowmax[8192] via DISTRIBUTED u64 atomicMax (64 ops
// per address over 8192 addresses - not R5's single-address serialization;
// max is order-independent -> deterministic). K1 zero-inits rowmax (packed
// keys of finite scores are > 0). 4 kernels -> 3: saves one ~15us boundary
// plus the 4 MB ppack round-trip.
// GEMM core byte-identical to R11..R16 (i8 16x16x64: 68us, MfmaUtil 20,
// 0 conflicts, absmax 0.0 across 6 rounds).
// Ledger: occupancy lever exhausted (R2/R5/R6), B-out-of-LDS loses (R4/R7),
// fp8 mfma_scale spills (R9), i8 2xK wins (R11), transposed/packed partials
// kill write amplification (R14/R15), algebraic neg^2 kills K3's gather
// (R16), single-address atomics +100us (R5), ticket+fence +20us (R10),
// cooperative launch no-ops under graph capture (R12).
#define BM 128
#define BN 128
#define BKB 64          // k elements (=bytes) per tile
#define KT (Dn / BKB)   // 8 k-iterations
#define NCT (Bn / BN)   // 64 column tiles
#define QS 256.0f
#define ISQ (2.0f / 65536.0f)

typedef int   int4v __attribute__((ext_vector_type(4)));
typedef float f32x4 __attribute__((ext_vector_type(4)));

// async global->LDS, 16B per lane; LDS dest is wave-uniform base + lane*16
__device__ __forceinline__ void async16(const void* g, void* l) {
    __builtin_amdgcn_global_load_lds(
        (const __attribute__((address_space(1))) void*)g,
        (__attribute__((address_space(3))) void*)l,
        16, 0, 0);
}

// pack (score, idx) into one sortable u64: key(f) monotonic in f, ~idx low
// so max() picks the SMALLEST index on score ties (reference semantics).
// For any finite score the key is nonzero, so 0 is the atomicMax identity.
__device__ __forceinline__ unsigned long long packSI(float s, int idx) {
    union { float f; unsigned u; } c; c.f = s;
    const unsigned key = (c.u & 0x80000000u) ? ~c.u : (c.u | 0x80000000u);
    return ((unsigned long long)key << 32) | (unsigned)(~idx);
}
__device__ __forceinline__ float unpackS(unsigned long long p) {
    unsigned key = (unsigned)(p >> 32);
    union { unsigned u; float f; } c;
    c.u = (key & 0x80000000u) ? (key ^ 0x80000000u) : ~key;
    return c.f;
}

// ---------------------------------------------------------------------------
// K1: one wave per row pair (a_i, p_i): L2-normalize both -> i8 rows (x256,
// RNE, clamp +-127), column term c[j] = -sp2[j] + 2*eps*sp[j], rowconst[i] =
// pos2 - sa2 - 2*eps*sa - D*eps^2 + MARGIN (exact fp32), and rowmax[i] = 0.
// 2048 blocks; at the HBM floor (~72 MB moved).
// ---------------------------------------------------------------------------
__global__ __launch_bounds__(256) void k_normalize(
    const float* __restrict__ x,
    uint8_t* __restrict__ a_i8, uint8_t* __restrict__ p_i8,
    float* __restrict__ cterm, float* __restrict__ rowconst,
    unsigned long long* __restrict__ rowmax)
{
    const int wave = threadIdx.x >> 6;
    const int lane = threadIdx.x & 63;
    const int i = blockIdx.x * 4 + wave;   // 0..8191

    const float* srcA = x + (size_t)i * (2 * Dn) + lane * 8;
    const float* srcP = srcA + Dn;
    float4 a0 = ((const float4*)srcA)[0];
    float4 a1 = ((const float4*)srcA)[1];
    float4 p0 = ((const float4*)srcP)[0];
    float4 p1 = ((const float4*)srcP)[1];
    float va[8] = {a0.x, a0.y, a0.z, a0.w, a1.x, a1.y, a1.z, a1.w};
    float vp[8] = {p0.x, p0.y, p0.z, p0.w, p1.x, p1.y, p1.z, p1.w};

    float ssa = 0.f, ssp = 0.f;
#pragma unroll
    for (int j = 0; j < 8; ++j) { ssa += va[j] * va[j]; ssp += vp[j] * vp[j]; }
#pragma unroll
    for (int m = 1; m < 64; m <<= 1) {
        ssa += __shfl_xor(ssa, m);
        ssp += __shfl_xor(ssp, m);
    }
    const float sa = 1.0f / fmaxf(sqrtf(ssa), EPSN);
    const float sp = 1.0f / fmaxf(sqrtf(ssp), EPSN);

    float oa[8], op[8];
    float s1p = 0.f, s2p = 0.f, s1a = 0.f, s2a = 0.f, pos = 0.f;
#pragma unroll
    for (int j = 0; j < 8; ++j) {
        oa[j] = va[j] * sa;
        op[j] = vp[j] * sp;
        s1p += op[j]; s2p += op[j] * op[j];
        s1a += oa[j]; s2a += oa[j] * oa[j];
        const float u = oa[j] - op[j] + EPSP;
        pos += u * u;
    }

    uint64_t pka = 0, pkp = 0;
#pragma unroll
    for (int j = 0; j < 8; ++j) {
        int qa = (int)rintf(oa[j] * QS);
        int qp = (int)rintf(op[j] * QS);
        qa = qa > 127 ? 127 : (qa < -127 ? -127 : qa);
        qp = qp > 127 ? 127 : (qp < -127 ? -127 : qp);
        pka |= (uint64_t)(uint8_t)qa << (8 * j);
        pkp |= (uint64_t)(uint8_t)qp << (8 * j);
    }
    *(uint64_t*)(a_i8 + (size_t)i * Dn + lane * 8) = pka;
    *(uint64_t*)(p_i8 + (size_t)i * Dn + lane * 8) = pkp;

#pragma unroll
    for (int m = 1; m < 64; m <<= 1) {
        s1p += __shfl_xor(s1p, m);
        s2p += __shfl_xor(s2p, m);
        s1a += __shfl_xor(s1a, m);
        s2a += __shfl_xor(s2a, m);
        pos += __shfl_xor(pos, m);
    }
    if (lane == 0) {
        cterm[i] = -s2p + 2.0f * EPSP * s1p;
        rowconst[i] = pos - s2a - 2.0f * EPSP * s1a
                      - (float)Dn * EPSP * EPSP + MARG;
        rowmax[i] = 0ull;            // atomicMax identity (poisoned otherwise)
    }
}

// ---------------------------------------------------------------------------
// K2: i8 MFMA GEMM (a_n @ p_n^T, x65536 scaled, exact int accumulate) +
// fused per-row argmax. K-loop byte-identical to R11..R16. Epilogue: packed
// u64 per-row tile-max -> ONE distributed atomicMax per (block,row).
// ---------------------------------------------------------------------------
__global__ __launch_bounds__(256, 4) void k_gemm_argmax(
    const uint8_t* __restrict__ a_i8, const uint8_t* __restrict__ p_i8,
    const float* __restrict__ cterm,
    unsigned long long* __restrict__ rowmax)
{
    __shared__ uint8_t As[2][BM * BKB];   // 2 x 8 KB
    __shared__ uint8_t Bs[2][BN * BKB];   // 2 x 8 KB
    __shared__ unsigned long long rp[2][BM];   // packed (score,idx)

    const int t = threadIdx.x;
    const int wave = t >> 6;
    const int lane = t & 63;
    const int rowBase = blockIdx.y * BM;
    const int colBase = blockIdx.x * BN;

    const int q = lane >> 4;       // 0..3  (k-chunk)
    const int m16 = lane & 15;     // 0..15
    const int waveRow = (wave >> 1) * 64;
    const int waveCol = (wave & 1) * 64;

    // staging pointers, hoisted (chunk c -> row c>>2, slot c&3 holds global
    // k-chunk (c&3)^((row>>1)&3))
    const int r0 = t >> 2;
    const int g0 = (t & 3) ^ ((r0 >> 1) & 3);
    const int r1 = (256 + t) >> 2;
    const int g1 = ((256 + t) & 3) ^ ((r1 >> 1) & 3);
    const uint8_t* gA0 = a_i8 + (size_t)(rowBase + r0) * Dn + g0 * 16;
    const uint8_t* gA1 = a_i8 + (size_t)(rowBase + r1) * Dn + g1 * 16;
    const uint8_t* gB0 = p_i8 + (size_t)(colBase + r0) * Dn + g0 * 16;
    const uint8_t* gB1 = p_i8 + (size_t)(colBase + r1) * Dn + g1 * 16;
    const int ldsC0 = (wave * 64) * 16;          // bytes; HW adds lane*16
    const int ldsC1 = (256 + wave * 64) * 16;

    // fragment LDS read bases: slot = q ^ ((m16>>1)&3) for ALL mt/nt
    const int s0 = q ^ ((m16 >> 1) & 3);
    const int aBase = (waveRow + m16) * BKB + s0 * 16;   // bytes
    const int bBase = (waveCol + m16) * BKB + s0 * 16;

    int4v acc[4][4];
#pragma unroll
    for (int a = 0; a < 4; ++a)
#pragma unroll
        for (int b = 0; b < 4; ++b) acc[a][b] = (int4v){0, 0, 0, 0};

    auto stage = [&](int buf, int ke) {      // ke = byte offset kt*64
        async16(gA0 + ke, &As[buf][ldsC0]);
        async16(gA1 + ke, &As[buf][ldsC1]);
        async16(gB0 + ke, &Bs[buf][ldsC0]);
        async16(gB1 + ke, &Bs[buf][ldsC1]);
    };

    stage(0, 0);
#pragma unroll
    for (int kt = 0; kt < KT; ++kt) {
        const int cur = kt & 1;
        __syncthreads();                 // tile kt resident; prior buf reads done
        if (kt + 1 < KT) stage(cur ^ 1, (kt + 1) * BKB);  // drains at NEXT barrier

        const uint8_t* pa = &As[cur][aBase];
        const uint8_t* pb = &Bs[cur][bBase];
        int4v af[4], bfr[4];
#pragma unroll
        for (int mt = 0; mt < 4; ++mt)
            af[mt] = *(const int4v*)(pa + mt * 16 * BKB);
#pragma unroll
        for (int nt = 0; nt < 4; ++nt)
            bfr[nt] = *(const int4v*)(pb + nt * 16 * BKB);
#pragma unroll
        for (int mt = 0; mt < 4; ++mt)
#pragma unroll
            for (int nt = 0; nt < 4; ++nt)
                acc[mt][nt] = __builtin_amdgcn_mfma_i32_16x16x64_i8(
                    af[mt], bfr[nt], acc[mt][nt], 0, 0, 0);
    }

    // epilogue: score = 2*idot/65536 + c[j]; mask diagonal; packed argmax
    float cv[4];
#pragma unroll
    for (int nt = 0; nt < 4; ++nt)
        cv[nt] = cterm[colBase + waveCol + nt * 16 + m16];

#pragma unroll
    for (int mt = 0; mt < 4; ++mt) {
#pragma unroll
        for (int v = 0; v < 4; ++v) {
            const int lr = waveRow + mt * 16 + q * 4 + v;   // C/D row = quad*4+reg
            const int gi = rowBase + lr;
            unsigned long long best = 0;   // key 0 = below any real score
#pragma unroll
            for (int nt = 0; nt < 4; ++nt) {
                const int gj = colBase + waveCol + nt * 16 + m16;  // col = lane&15
                float sc = ISQ * (float)acc[mt][nt][v] + cv[nt];
                unsigned long long pk = (gj == gi) ? 0ull : packSI(sc, gj);
                best = pk > best ? pk : best;
            }
#pragma unroll
            for (int msk = 1; msk < 16; msk <<= 1) {       // reduce over 16 cols
                unsigned long long ob = __shfl_xor(best, msk);
                best = ob > best ? ob : best;
            }
            if (m16 == 0) rp[wave & 1][lr] = best;
        }
    }
    __syncthreads();
    if (t < BM) {
        unsigned long long b0 = rp[0][t];
        unsigned long long b1 = rp[1][t];
        if (b1 > b0) b0 = b1;
        // distributed per-row max: 64 blocks contend per address (order-
        // independent -> deterministic), 8192 addresses total.
        atomicMax(&rowmax[rowBase + t], b0);
    }
}

// ---------------------------------------------------------------------------
// K3: single block - loss = mean(relu(rowconst[i] + score_max[i])).
// Reads 96 KB; deterministic fixed-order sums.
// ---------------------------------------------------------------------------
__global__ __launch_bounds__(1024) void k_final(
    const unsigned long long* __restrict__ rowmax,
    const float* __restrict__ rowconst,
    float* __restrict__ out)
{
    __shared__ float sm[16];
    float s = 0.f;
    for (int k = threadIdx.x; k < Bn; k += 1024)
        s += fmaxf(rowconst[k] + unpackS(rowmax[k]), 0.f);
#pragma unroll
    for (int msk = 1; msk < 64; msk <<= 1) s += __shfl_xor(s, msk);
    if ((threadIdx.x & 63) == 0) sm[threadIdx.x >> 6] = s;
    __syncthreads();
    if (threadIdx.x == 0) {
        float tot = 0.f;
#pragma unroll
        for (int w = 0; w < 16; ++w) tot += sm[w];
        out[0] = tot * (1.0f / Bn);
    }
}

extern "C" void kernel_launch(void* const* d_in, const int* in_sizes, int n_in,
                              void* d_out, int out_size, void* d_ws, size_t ws_size,
                              hipStream_t stream)
{
    const float* x = (const float*)d_in[0];
    char* ws = (char*)d_ws;
    // workspace layout (bytes):
    uint8_t*  a_i8     = (uint8_t*)(ws + 0);         // 4 MB
    uint8_t*  p_i8     = (uint8_t*)(ws + 4194304);   // 4 MB
    float*    cterm    = (float*)(ws + 8388608);     // 32 KB
    float*    rowconst = (float*)(ws + 8421376);     // 32 KB
    unsigned long long* rowmax =
        (unsigned long long*)(ws + 8454144);         // 64 KB (total ~8.5 MB)
    float*    out      = (float*)d_out;

    k_normalize<<<2048, 256, 0, stream>>>(x, a_i8, p_i8, cterm, rowconst, rowmax);
    k_gemm_argmax<<<dim3(NCT, Bn / BM), 256, 0, stream>>>(a_i8, p_i8, cterm, rowmax);
    k_final<<<1, 1024, 0, stream>>>(rowmax, rowconst, out);
}